// Round 1
// baseline (4925.968 us; speedup 1.0000x reference)
//
#include <hip/hip_runtime.h>
#include <math.h>

#define NN 16384
#define H 128
#define CODE 1024
#define MAXDEG 26
#define SE_STRIDE 260   // floats; 260*4=1040 bytes, 16B-aligned rows

__device__ __forceinline__ float silu(float x) {
    return x / (1.0f + __expf(-x));
}

// row_ptr via binary search on sorted rows; deg_inv from out-degree (== in-degree, symmetric graph)
__global__ void k_rowptr(const int* __restrict__ rows, int E,
                         int* __restrict__ rowptr, float* __restrict__ deginv) {
    int n = blockIdx.x * blockDim.x + threadIdx.x;
    if (n > NN) return;
    int lo = 0, hi = E;
    while (lo < hi) { int mid = (lo + hi) >> 1; if (rows[mid] < n) lo = mid + 1; else hi = mid; }
    rowptr[n] = lo;
    if (n < NN) {
        int lo2 = lo, hi2 = E;
        while (lo2 < hi2) { int mid = (lo2 + hi2) >> 1; if (rows[mid] < n + 1) lo2 = mid + 1; else hi2 = mid; }
        int d = lo2 - lo; if (d < 1) d = 1;
        deginv[n] = 1.0f / (float)d;
    }
}

// h = y @ W_in + b_in   (8 nodes per block, 128 threads)
__global__ void k_in(const float* __restrict__ y, const float* __restrict__ W,
                     const float* __restrict__ bi, float* __restrict__ h) {
    __shared__ float sy[8 * CODE];      // 32 KB
    int n0 = blockIdx.x * 8;
    int tid = threadIdx.x;
    const float4* src = (const float4*)(y + (size_t)n0 * CODE);
    float4* dst = (float4*)sy;
    for (int i = tid; i < 8 * CODE / 4; i += 128) dst[i] = src[i];
    __syncthreads();
    float acc[8];
    float bj = bi[tid];
#pragma unroll
    for (int i = 0; i < 8; i++) acc[i] = bj;
    for (int k = 0; k < CODE; k += 4) {
        float w0 = W[(k+0)*H + tid], w1 = W[(k+1)*H + tid];
        float w2 = W[(k+2)*H + tid], w3 = W[(k+3)*H + tid];
#pragma unroll
        for (int i = 0; i < 8; i++) {
            float4 v = *(const float4*)&sy[i * CODE + k];
            acc[i] = fmaf(v.x, w0, acc[i]); acc[i] = fmaf(v.y, w1, acc[i]);
            acc[i] = fmaf(v.z, w2, acc[i]); acc[i] = fmaf(v.w, w3, acc[i]);
        }
    }
#pragma unroll
    for (int i = 0; i < 8; i++) h[(size_t)(n0 + i) * H + tid] = acc[i];
}

// LayerNorm, one wave per node, 4 nodes per 256-thread block
__global__ void k_ln(const float* __restrict__ h, const float* __restrict__ g,
                     const float* __restrict__ b, float* __restrict__ hn) {
    int wave = threadIdx.x >> 6, lane = threadIdx.x & 63;
    int n = blockIdx.x * 4 + wave;
    const float* hr = h + (size_t)n * H;
    float x0 = hr[lane], x1 = hr[lane + 64];
    float s = x0 + x1;
#pragma unroll
    for (int off = 32; off; off >>= 1) s += __shfl_xor(s, off);
    float mu = s * (1.0f / 128.0f);
    float d0 = x0 - mu, d1 = x1 - mu;
    float v = d0 * d0 + d1 * d1;
#pragma unroll
    for (int off = 32; off; off >>= 1) v += __shfl_xor(v, off);
    float rs = rsqrtf(v * (1.0f / 128.0f) + 1e-5f);
    float* o = hn + (size_t)n * H;
    o[lane]      = d0 * rs * g[lane]      + b[lane];
    o[lane + 64] = d1 * rs * g[lane + 64] + b[lane + 64];
}

// Edge MLP + deterministic gather-aggregation: one block per destination node.
// Uses graph symmetry: agg[n] = sum over out-edges (n,c) of MLP([hn[c], hn[n], dist]).
__global__ void k_edge(const float* __restrict__ hn, const float* __restrict__ gc,
                       const int* __restrict__ cols, const int* __restrict__ rowptr,
                       const float* __restrict__ deginv,
                       const float* __restrict__ W1, const float* __restrict__ b1,
                       const float* __restrict__ W2, const float* __restrict__ b2,
                       float* __restrict__ agg) {
    __shared__ float se[MAXDEG * SE_STRIDE];   // ~27 KB
    int n = blockIdx.x;
    int tid = threadIdx.x;
    int e0 = rowptr[n], e1 = rowptr[n + 1];
    float nx = gc[n * 3], ny = gc[n * 3 + 1], nz = gc[n * 3 + 2];
    float hn_n_t = hn[(size_t)n * H + tid];
    float b1j = b1[tid], b2j = b2[tid];
    float sum = 0.0f;

    for (int base = e0; base < e1; base += MAXDEG) {
        int deg = min(e1 - base, MAXDEG);
        for (int e = 0; e < deg; e++) {
            int c = cols[base + e];
            se[e * SE_STRIDE + tid]       = hn[(size_t)c * H + tid];   // hn[row=c]
            se[e * SE_STRIDE + 128 + tid] = hn_n_t;                    // hn[col=n]
            if (tid == 0) {
                float dx = nx - gc[c * 3], dy = ny - gc[c * 3 + 1], dz = nz - gc[c * 3 + 2];
                se[e * SE_STRIDE + 256] = sqrtf(dx * dx + dy * dy + dz * dz);
            }
        }
        __syncthreads();

        float acc[MAXDEG];
#pragma unroll
        for (int e = 0; e < MAXDEG; e++) acc[e] = b1j;
        for (int k = 0; k < 256; k += 4) {
            float w0 = W1[(k+0)*H + tid], w1 = W1[(k+1)*H + tid];
            float w2 = W1[(k+2)*H + tid], w3 = W1[(k+3)*H + tid];
#pragma unroll
            for (int e = 0; e < MAXDEG; e++) {
                float4 v = *(const float4*)&se[e * SE_STRIDE + k];
                acc[e] = fmaf(v.x, w0, acc[e]); acc[e] = fmaf(v.y, w1, acc[e]);
                acc[e] = fmaf(v.z, w2, acc[e]); acc[e] = fmaf(v.w, w3, acc[e]);
            }
        }
        {
            float w256 = W1[256 * H + tid];
#pragma unroll
            for (int e = 0; e < MAXDEG; e++)
                acc[e] = fmaf(se[e * SE_STRIDE + 256], w256, acc[e]);
        }
        __syncthreads();
#pragma unroll
        for (int e = 0; e < MAXDEG; e++) se[e * SE_STRIDE + tid] = silu(acc[e]);
        __syncthreads();
#pragma unroll
        for (int e = 0; e < MAXDEG; e++) acc[e] = b2j;
        for (int k = 0; k < 128; k += 4) {
            float w0 = W2[(k+0)*H + tid], w1 = W2[(k+1)*H + tid];
            float w2 = W2[(k+2)*H + tid], w3 = W2[(k+3)*H + tid];
#pragma unroll
            for (int e = 0; e < MAXDEG; e++) {
                float4 v = *(const float4*)&se[e * SE_STRIDE + k];
                acc[e] = fmaf(v.x, w0, acc[e]); acc[e] = fmaf(v.y, w1, acc[e]);
                acc[e] = fmaf(v.z, w2, acc[e]); acc[e] = fmaf(v.w, w3, acc[e]);
            }
        }
#pragma unroll
        for (int e = 0; e < MAXDEG; e++)
            if (e < deg) sum += silu(acc[e]);
        __syncthreads();   // before next chunk overwrites se
    }
    agg[(size_t)n * H + tid] = sum * deginv[n];
}

// Node MLP + residual: h = hn + (silu([hn,agg] @ nW1 + nb1) @ nW2 + nb2)
__global__ void k_node(const float* __restrict__ hn, const float* __restrict__ agg,
                       const float* __restrict__ W1, const float* __restrict__ b1,
                       const float* __restrict__ W2, const float* __restrict__ b2,
                       float* __restrict__ h) {
    __shared__ float sx[8 * 256];   // 8 KB: [hn, agg] per node
    __shared__ float sm[8 * 128];   // 4 KB: m1
    int n0 = blockIdx.x * 8;
    int tid = threadIdx.x;
#pragma unroll
    for (int i = 0; i < 8; i++) {
        sx[i * 256 + tid]       = hn[(size_t)(n0 + i) * H + tid];
        sx[i * 256 + 128 + tid] = agg[(size_t)(n0 + i) * H + tid];
    }
    __syncthreads();
    float acc[8];
    float b1j = b1[tid];
#pragma unroll
    for (int i = 0; i < 8; i++) acc[i] = b1j;
    for (int k = 0; k < 256; k += 4) {
        float w0 = W1[(k+0)*H + tid], w1 = W1[(k+1)*H + tid];
        float w2 = W1[(k+2)*H + tid], w3 = W1[(k+3)*H + tid];
#pragma unroll
        for (int i = 0; i < 8; i++) {
            float4 v = *(const float4*)&sx[i * 256 + k];
            acc[i] = fmaf(v.x, w0, acc[i]); acc[i] = fmaf(v.y, w1, acc[i]);
            acc[i] = fmaf(v.z, w2, acc[i]); acc[i] = fmaf(v.w, w3, acc[i]);
        }
    }
#pragma unroll
    for (int i = 0; i < 8; i++) sm[i * 128 + tid] = silu(acc[i]);
    __syncthreads();
    float b2j = b2[tid];
#pragma unroll
    for (int i = 0; i < 8; i++) acc[i] = b2j;
    for (int k = 0; k < 128; k += 4) {
        float w0 = W2[(k+0)*H + tid], w1 = W2[(k+1)*H + tid];
        float w2 = W2[(k+2)*H + tid], w3 = W2[(k+3)*H + tid];
#pragma unroll
        for (int i = 0; i < 8; i++) {
            float4 v = *(const float4*)&sm[i * 128 + k];
            acc[i] = fmaf(v.x, w0, acc[i]); acc[i] = fmaf(v.y, w1, acc[i]);
            acc[i] = fmaf(v.z, w2, acc[i]); acc[i] = fmaf(v.w, w3, acc[i]);
        }
    }
#pragma unroll
    for (int i = 0; i < 8; i++)
        h[(size_t)(n0 + i) * H + tid] = sx[i * 256 + tid] + acc[i];   // residual from hn
}

// out = h @ W_out + b_out  (4 nodes per 256-thread block, 4 cols per thread)
__global__ void k_out(const float* __restrict__ h, const float* __restrict__ W,
                      const float* __restrict__ bo, float* __restrict__ out) {
    __shared__ float sh[4 * 128];
    int n0 = blockIdx.x * 4;
    int tid = threadIdx.x;   // 256
    for (int i = tid; i < 4 * 128; i += 256) {
        int node = i >> 7, k = i & 127;
        sh[i] = h[(size_t)(n0 + node) * H + k];
    }
    __syncthreads();
    float acc[4][4];
#pragma unroll
    for (int i = 0; i < 4; i++)
#pragma unroll
        for (int c = 0; c < 4; c++) acc[i][c] = bo[c * 256 + tid];
    for (int k = 0; k < 128; k++) {
        float w0 = W[k * 1024 + tid],       w1 = W[k * 1024 + 256 + tid];
        float w2 = W[k * 1024 + 512 + tid], w3 = W[k * 1024 + 768 + tid];
#pragma unroll
        for (int i = 0; i < 4; i++) {
            float hv = sh[i * 128 + k];
            acc[i][0] = fmaf(hv, w0, acc[i][0]); acc[i][1] = fmaf(hv, w1, acc[i][1]);
            acc[i][2] = fmaf(hv, w2, acc[i][2]); acc[i][3] = fmaf(hv, w3, acc[i][3]);
        }
    }
#pragma unroll
    for (int i = 0; i < 4; i++)
#pragma unroll
        for (int c = 0; c < 4; c++)
            out[(size_t)(n0 + i) * 1024 + c * 256 + tid] = acc[i][c];
}

extern "C" void kernel_launch(void* const* d_in, const int* in_sizes, int n_in,
                              void* d_out, int out_size, void* d_ws, size_t ws_size,
                              hipStream_t stream) {
    const float* y     = (const float*)d_in[0];
    const float* gc    = (const float*)d_in[1];
    const int*   ei    = (const int*)  d_in[2];
    const float* W_in  = (const float*)d_in[3];
    const float* b_in  = (const float*)d_in[4];
    const float* ln_g  = (const float*)d_in[5];
    const float* ln_b  = (const float*)d_in[6];
    const float* eW1   = (const float*)d_in[7];
    const float* eb1   = (const float*)d_in[8];
    const float* eW2   = (const float*)d_in[9];
    const float* eb2   = (const float*)d_in[10];
    const float* nW1   = (const float*)d_in[11];
    const float* nb1   = (const float*)d_in[12];
    const float* nW2   = (const float*)d_in[13];
    const float* nb2   = (const float*)d_in[14];
    const float* W_out = (const float*)d_in[15];
    const float* b_out = (const float*)d_in[16];

    int E = in_sizes[2] / 2;
    const int* rows = ei;
    const int* cols = ei + E;

    float* ws    = (float*)d_ws;
    float* h     = ws;                          // NN*H floats
    float* hn    = h   + (size_t)NN * H;        // NN*H
    float* agg   = hn  + (size_t)NN * H;        // NN*H
    float* deginv= agg + (size_t)NN * H;        // NN
    int*   rowptr= (int*)(deginv + NN);         // NN+1

    k_rowptr<<<(NN + 1 + 255) / 256, 256, 0, stream>>>(rows, E, rowptr, deginv);
    k_in<<<NN / 8, 128, 0, stream>>>(y, W_in, b_in, h);
    for (int l = 0; l < 4; ++l) {
        k_ln<<<NN / 4, 256, 0, stream>>>(h, ln_g + l * H, ln_b + l * H, hn);
        k_edge<<<NN, 128, 0, stream>>>(hn, gc, cols, rowptr, deginv,
                                       eW1 + (size_t)l * 257 * H, eb1 + l * H,
                                       eW2 + (size_t)l * H * H,   eb2 + l * H, agg);
        k_node<<<NN / 8, 128, 0, stream>>>(hn, agg,
                                           nW1 + (size_t)l * 256 * H, nb1 + l * H,
                                           nW2 + (size_t)l * H * H,   nb2 + l * H, h);
    }
    k_out<<<NN / 4, 256, 0, stream>>>(h, W_out, b_out, (float*)d_out);
}

// Round 2
// 1103.280 us; speedup vs baseline: 4.4648x; 4.4648x over previous
//
#include <hip/hip_runtime.h>
#include <math.h>

#define NN 16384
#define H 128
#define CODE 1024

typedef __attribute__((ext_vector_type(8))) short short8;
typedef __attribute__((ext_vector_type(4))) float f32x4;

__device__ __forceinline__ float silu(float x) {
    return x / (1.0f + __expf(-x));
}

// float -> bf16 (RNE), bit trick; deterministic
__device__ __forceinline__ unsigned short f2bf(float f) {
    unsigned int u = __float_as_uint(f);
    u = (u + 0x7FFFu + ((u >> 16) & 1u)) >> 16;
    return (unsigned short)u;
}

// ---------------- graph preprocessing ----------------
__global__ void k_rowptr(const int* __restrict__ rows, int E,
                         int* __restrict__ rowptr, float* __restrict__ deginv) {
    int n = blockIdx.x * blockDim.x + threadIdx.x;
    if (n > NN) return;
    int lo = 0, hi = E;
    while (lo < hi) { int mid = (lo + hi) >> 1; if (rows[mid] < n) lo = mid + 1; else hi = mid; }
    rowptr[n] = lo;
    if (n < NN) {
        int lo2 = lo, hi2 = E;
        while (lo2 < hi2) { int mid = (lo2 + hi2) >> 1; if (rows[mid] < n + 1) lo2 = mid + 1; else hi2 = mid; }
        int d = lo2 - lo; if (d < 1) d = 1;
        deginv[n] = 1.0f / (float)d;
    }
}

// Build the eW2^T bf16 LDS image (row n = output col, 272B padded stride), once.
// image[l] byte (n*272 + 2k) = bf16(eW2[l][k][n])
__global__ void k_prepw2(const float* __restrict__ eW2, char* __restrict__ w2img) {
    int t = blockIdx.x * 256 + threadIdx.x;
    if (t >= 4 * 128 * 128) return;
    int l = t >> 14, r = t & 16383;
    int k = r >> 7, n = r & 127;
    float v = eW2[l * 16384 + k * 128 + n];
    *(unsigned short*)(w2img + (size_t)l * 34816 + n * 272 + 2 * k) = f2bf(v);
}

// ---------------- h = y @ W_in + b_in ----------------
__global__ void k_in(const float* __restrict__ y, const float* __restrict__ W,
                     const float* __restrict__ bi, float* __restrict__ h) {
    __shared__ float sy[8 * CODE];
    int n0 = blockIdx.x * 8;
    int tid = threadIdx.x;
    const float4* src = (const float4*)(y + (size_t)n0 * CODE);
    float4* dst = (float4*)sy;
    for (int i = tid; i < 8 * CODE / 4; i += 128) dst[i] = src[i];
    __syncthreads();
    float acc[8];
    float bj = bi[tid];
#pragma unroll
    for (int i = 0; i < 8; i++) acc[i] = bj;
    for (int k = 0; k < CODE; k += 4) {
        float w0 = W[(k+0)*H + tid], w1 = W[(k+1)*H + tid];
        float w2 = W[(k+2)*H + tid], w3 = W[(k+3)*H + tid];
#pragma unroll
        for (int i = 0; i < 8; i++) {
            float4 v = *(const float4*)&sy[i * CODE + k];
            acc[i] = fmaf(v.x, w0, acc[i]); acc[i] = fmaf(v.y, w1, acc[i]);
            acc[i] = fmaf(v.z, w2, acc[i]); acc[i] = fmaf(v.w, w3, acc[i]);
        }
    }
#pragma unroll
    for (int i = 0; i < 8; i++) h[(size_t)(n0 + i) * H + tid] = acc[i];
}

// ---------------- LayerNorm ----------------
__global__ void k_ln(const float* __restrict__ h, const float* __restrict__ g,
                     const float* __restrict__ b, float* __restrict__ hn) {
    int wave = threadIdx.x >> 6, lane = threadIdx.x & 63;
    int n = blockIdx.x * 4 + wave;
    const float* hr = h + (size_t)n * H;
    float x0 = hr[lane], x1 = hr[lane + 64];
    float s = x0 + x1;
#pragma unroll
    for (int off = 32; off; off >>= 1) s += __shfl_xor(s, off);
    float mu = s * (1.0f / 128.0f);
    float d0 = x0 - mu, d1 = x1 - mu;
    float v = d0 * d0 + d1 * d1;
#pragma unroll
    for (int off = 32; off; off >>= 1) v += __shfl_xor(v, off);
    float rs = rsqrtf(v * (1.0f / 128.0f) + 1e-5f);
    float* o = hn + (size_t)n * H;
    o[lane]      = d0 * rs * g[lane]      + b[lane];
    o[lane + 64] = d1 * rs * g[lane + 64] + b[lane + 64];
}

// ---------------- P = hn @ [W1a | W1b], P2 gets +b1 ----------------
// P[n][j]      = sum_k hn[n][k] * eW1[k][j]          (row-slot part, gathered by neighbor)
// P[n][128+j]  = sum_k hn[n][k] * eW1[128+k][j] + b1 (col-slot part, fixed per node)
__global__ __launch_bounds__(128) void k_P(const float* __restrict__ hn,
                                           const float* __restrict__ W1,
                                           const float* __restrict__ b1,
                                           float* __restrict__ P) {
    __shared__ float sh[8 * 128];
    int n0 = blockIdx.x * 8;
    int tid = threadIdx.x;
    const float4* src = (const float4*)(hn + (size_t)n0 * H);
    float4* dst = (float4*)sh;
#pragma unroll
    for (int i = 0; i < 2; i++) dst[tid + i * 128] = src[tid + i * 128];
    __syncthreads();
    float acc0[8], acc1[8];
    float bb = b1[tid];
#pragma unroll
    for (int i = 0; i < 8; i++) { acc0[i] = 0.0f; acc1[i] = bb; }
    for (int k = 0; k < 128; k += 4) {
        float wa0 = W1[(k+0)*H + tid], wa1 = W1[(k+1)*H + tid];
        float wa2 = W1[(k+2)*H + tid], wa3 = W1[(k+3)*H + tid];
        float wb0 = W1[(128+k+0)*H + tid], wb1 = W1[(128+k+1)*H + tid];
        float wb2 = W1[(128+k+2)*H + tid], wb3 = W1[(128+k+3)*H + tid];
#pragma unroll
        for (int i = 0; i < 8; i++) {
            float4 v = *(const float4*)&sh[i * 128 + k];
            acc0[i] = fmaf(v.x, wa0, acc0[i]); acc0[i] = fmaf(v.y, wa1, acc0[i]);
            acc0[i] = fmaf(v.z, wa2, acc0[i]); acc0[i] = fmaf(v.w, wa3, acc0[i]);
            acc1[i] = fmaf(v.x, wb0, acc1[i]); acc1[i] = fmaf(v.y, wb1, acc1[i]);
            acc1[i] = fmaf(v.z, wb2, acc1[i]); acc1[i] = fmaf(v.w, wb3, acc1[i]);
        }
    }
#pragma unroll
    for (int i = 0; i < 8; i++) {
        P[(size_t)(n0 + i) * 256 + tid]       = acc0[i];
        P[(size_t)(n0 + i) * 256 + 128 + tid] = acc1[i];
    }
}

// ---------------- fused edge MLP + aggregation (MFMA) ----------------
// One wave per destination node. m1[e] = silu(P1[c] + P2[n] + dist*w256) (b1 folded in P2),
// then [32x128]@[128x128] bf16 MFMA with eW2^T, bias+silu+row-sum epilogue.
__global__ __launch_bounds__(128) void k_edge_mfma(
        const float* __restrict__ P, const float* __restrict__ gc,
        const int* __restrict__ cols, const int* __restrict__ rowptr,
        const float* __restrict__ deginv, const char* __restrict__ w2img,
        const float* __restrict__ w256, const float* __restrict__ b2,
        float* __restrict__ agg) {
    __shared__ __align__(16) char sBt[128 * 272];      // eW2^T bf16, padded stride
    __shared__ __align__(16) char sA[2][32 * 272];     // m1 bf16 per wave
    __shared__ int   s_sc[2][32];
    __shared__ float s_sd[2][32];

    int tid = threadIdx.x;
    int wave = tid >> 6, lane = tid & 63;
    int n = blockIdx.x * 2 + wave;

    // stage eW2^T image -> LDS (linear uint4 copy)
    {
        const uint4* src = (const uint4*)w2img;
        uint4* dst = (uint4*)sBt;
        for (int i = tid; i < 128 * 272 / 16; i += 128) dst[i] = src[i];
    }

    int e0 = rowptr[n];
    int deg = rowptr[n + 1] - e0;

    if (lane < 32) {
        bool v = lane < deg;
        int c = v ? cols[e0 + lane] : n;
        s_sc[wave][lane] = c;
        float dx = gc[3 * n] - gc[3 * c];
        float dy = gc[3 * n + 1] - gc[3 * c + 1];
        float dz = gc[3 * n + 2] - gc[3 * c + 2];
        s_sd[wave][lane] = v ? sqrtf(dx * dx + dy * dy + dz * dz) : 0.0f;
    }

    int j0 = lane, j1 = lane + 64;
    float p2a = P[(size_t)n * 256 + 128 + j0];
    float p2b = P[(size_t)n * 256 + 128 + j1];
    float wa = w256[j0], wb = w256[j1];

#pragma unroll 8
    for (int e = 0; e < 32; e++) {
        int c = s_sc[wave][e];
        float d = s_sd[wave][e];
        float va = P[(size_t)c * 256 + j0] + p2a + d * wa;
        float vb = P[(size_t)c * 256 + j1] + p2b + d * wb;
        va = silu(va); vb = silu(vb);
        bool valid = e < deg;
        unsigned short ba = valid ? f2bf(va) : (unsigned short)0;
        unsigned short bb = valid ? f2bf(vb) : (unsigned short)0;
        *(unsigned short*)(&sA[wave][e * 272 + 2 * j0]) = ba;
        *(unsigned short*)(&sA[wave][e * 272 + 2 * j1]) = bb;
    }
    __syncthreads();

    // MFMA: M=32 (2 tiles), N=128 (8 tiles), K=128 (4 steps)
    int r15 = lane & 15;
    int krow = lane >> 4;
    f32x4 acc[2][8];
#pragma unroll
    for (int mt = 0; mt < 2; mt++)
#pragma unroll
        for (int nt = 0; nt < 8; nt++) {
            f32x4 z = {0.f, 0.f, 0.f, 0.f};
            acc[mt][nt] = z;
        }

#pragma unroll
    for (int ks = 0; ks < 4; ks++) {
        int kb = ks * 64 + krow * 16;   // byte offset of this lane's 8 bf16
        short8 a0 = *(const short8*)(&sA[wave][r15 * 272 + kb]);
        short8 a1 = *(const short8*)(&sA[wave][(r15 + 16) * 272 + kb]);
#pragma unroll
        for (int nt = 0; nt < 8; nt++) {
            short8 bfr = *(const short8*)(&sBt[(nt * 16 + r15) * 272 + kb]);
            acc[0][nt] = __builtin_amdgcn_mfma_f32_16x16x32_bf16(a0, bfr, acc[0][nt], 0, 0, 0);
            acc[1][nt] = __builtin_amdgcn_mfma_f32_16x16x32_bf16(a1, bfr, acc[1][nt], 0, 0, 0);
        }
    }

    // epilogue: +b2, silu, sum valid rows, * deginv
    float dinv = deginv[n];
    float b2v[8];
#pragma unroll
    for (int nt = 0; nt < 8; nt++) b2v[nt] = b2[nt * 16 + r15];

#pragma unroll
    for (int nt = 0; nt < 8; nt++) {
        float s = 0.0f;
#pragma unroll
        for (int mt = 0; mt < 2; mt++) {
            int rbase = krow * 4 + mt * 16;
#pragma unroll
            for (int r = 0; r < 4; r++) {
                float v = acc[mt][nt][r] + b2v[nt];
                v = silu(v);
                s += ((rbase + r) < deg) ? v : 0.0f;
            }
        }
        s += __shfl_xor(s, 16);
        s += __shfl_xor(s, 32);
        if (lane < 16) agg[(size_t)n * H + nt * 16 + lane] = s * dinv;
    }
}

// ---------------- node MLP + residual ----------------
__global__ void k_node(const float* __restrict__ hn, const float* __restrict__ agg,
                       const float* __restrict__ W1, const float* __restrict__ b1,
                       const float* __restrict__ W2, const float* __restrict__ b2,
                       float* __restrict__ h) {
    __shared__ float sx[8 * 256];
    __shared__ float sm[8 * 128];
    int n0 = blockIdx.x * 8;
    int tid = threadIdx.x;
#pragma unroll
    for (int i = 0; i < 8; i++) {
        sx[i * 256 + tid]       = hn[(size_t)(n0 + i) * H + tid];
        sx[i * 256 + 128 + tid] = agg[(size_t)(n0 + i) * H + tid];
    }
    __syncthreads();
    float acc[8];
    float b1j = b1[tid];
#pragma unroll
    for (int i = 0; i < 8; i++) acc[i] = b1j;
    for (int k = 0; k < 256; k += 4) {
        float w0 = W1[(k+0)*H + tid], w1 = W1[(k+1)*H + tid];
        float w2 = W1[(k+2)*H + tid], w3 = W1[(k+3)*H + tid];
#pragma unroll
        for (int i = 0; i < 8; i++) {
            float4 v = *(const float4*)&sx[i * 256 + k];
            acc[i] = fmaf(v.x, w0, acc[i]); acc[i] = fmaf(v.y, w1, acc[i]);
            acc[i] = fmaf(v.z, w2, acc[i]); acc[i] = fmaf(v.w, w3, acc[i]);
        }
    }
#pragma unroll
    for (int i = 0; i < 8; i++) sm[i * 128 + tid] = silu(acc[i]);
    __syncthreads();
    float b2j = b2[tid];
#pragma unroll
    for (int i = 0; i < 8; i++) acc[i] = b2j;
    for (int k = 0; k < 128; k += 4) {
        float w0 = W2[(k+0)*H + tid], w1 = W2[(k+1)*H + tid];
        float w2 = W2[(k+2)*H + tid], w3 = W2[(k+3)*H + tid];
#pragma unroll
        for (int i = 0; i < 8; i++) {
            float4 v = *(const float4*)&sm[i * 128 + k];
            acc[i] = fmaf(v.x, w0, acc[i]); acc[i] = fmaf(v.y, w1, acc[i]);
            acc[i] = fmaf(v.z, w2, acc[i]); acc[i] = fmaf(v.w, w3, acc[i]);
        }
    }
#pragma unroll
    for (int i = 0; i < 8; i++)
        h[(size_t)(n0 + i) * H + tid] = sx[i * 256 + tid] + acc[i];
}

// ---------------- out = h @ W_out + b_out ----------------
__global__ void k_out(const float* __restrict__ h, const float* __restrict__ W,
                      const float* __restrict__ bo, float* __restrict__ out) {
    __shared__ float sh[4 * 128];
    int n0 = blockIdx.x * 4;
    int tid = threadIdx.x;
    for (int i = tid; i < 4 * 128; i += 256) {
        int node = i >> 7, k = i & 127;
        sh[i] = h[(size_t)(n0 + node) * H + k];
    }
    __syncthreads();
    float acc[4][4];
#pragma unroll
    for (int i = 0; i < 4; i++)
#pragma unroll
        for (int c = 0; c < 4; c++) acc[i][c] = bo[c * 256 + tid];
    for (int k = 0; k < 128; k++) {
        float w0 = W[k * 1024 + tid],       w1 = W[k * 1024 + 256 + tid];
        float w2 = W[k * 1024 + 512 + tid], w3 = W[k * 1024 + 768 + tid];
#pragma unroll
        for (int i = 0; i < 4; i++) {
            float hv = sh[i * 128 + k];
            acc[i][0] = fmaf(hv, w0, acc[i][0]); acc[i][1] = fmaf(hv, w1, acc[i][1]);
            acc[i][2] = fmaf(hv, w2, acc[i][2]); acc[i][3] = fmaf(hv, w3, acc[i][3]);
        }
    }
#pragma unroll
    for (int i = 0; i < 4; i++)
#pragma unroll
        for (int c = 0; c < 4; c++)
            out[(size_t)(n0 + i) * 1024 + c * 256 + tid] = acc[i][c];
}

extern "C" void kernel_launch(void* const* d_in, const int* in_sizes, int n_in,
                              void* d_out, int out_size, void* d_ws, size_t ws_size,
                              hipStream_t stream) {
    const float* y     = (const float*)d_in[0];
    const float* gc    = (const float*)d_in[1];
    const int*   ei    = (const int*)  d_in[2];
    const float* W_in  = (const float*)d_in[3];
    const float* b_in  = (const float*)d_in[4];
    const float* ln_g  = (const float*)d_in[5];
    const float* ln_b  = (const float*)d_in[6];
    const float* eW1   = (const float*)d_in[7];
    const float* eb1   = (const float*)d_in[8];
    const float* eW2   = (const float*)d_in[9];
    const float* eb2   = (const float*)d_in[10];
    const float* nW1   = (const float*)d_in[11];
    const float* nb1   = (const float*)d_in[12];
    const float* nW2   = (const float*)d_in[13];
    const float* nb2   = (const float*)d_in[14];
    const float* W_out = (const float*)d_in[15];
    const float* b_out = (const float*)d_in[16];

    int E = in_sizes[2] / 2;
    const int* rows = ei;
    const int* cols = ei + E;

    char* wsb   = (char*)d_ws;
    char* w2img = wsb;                               // 4 * 34816 bytes
    float* fbase = (float*)(wsb + 4 * 34816);
    float* h      = fbase;                           // NN*H
    float* hn     = h   + (size_t)NN * H;            // NN*H
    float* agg    = hn  + (size_t)NN * H;            // NN*H
    float* P      = agg + (size_t)NN * H;            // NN*256
    float* deginv = P   + (size_t)NN * 256;          // NN
    int*   rowptr = (int*)(deginv + NN);             // NN+1

    k_prepw2<<<(4 * 128 * 128 + 255) / 256, 256, 0, stream>>>(eW2, w2img);
    k_rowptr<<<(NN + 1 + 255) / 256, 256, 0, stream>>>(rows, E, rowptr, deginv);
    k_in<<<NN / 8, 128, 0, stream>>>(y, W_in, b_in, h);
    for (int l = 0; l < 4; ++l) {
        k_ln<<<NN / 4, 256, 0, stream>>>(h, ln_g + l * H, ln_b + l * H, hn);
        k_P<<<NN / 8, 128, 0, stream>>>(hn, eW1 + (size_t)l * 257 * H, eb1 + l * H, P);
        k_edge_mfma<<<NN / 2, 128, 0, stream>>>(P, gc, cols, rowptr, deginv,
                                                w2img + (size_t)l * 34816,
                                                eW1 + (size_t)l * 257 * H + 256 * H,
                                                eb2 + l * H, agg);
        k_node<<<NN / 8, 128, 0, stream>>>(hn, agg,
                                           nW1 + (size_t)l * 256 * H, nb1 + l * H,
                                           nW2 + (size_t)l * H * H,   nb2 + l * H, h);
    }
    k_out<<<NN / 4, 256, 0, stream>>>(h, W_out, b_out, (float*)d_out);
}

// Round 3
// 913.455 us; speedup vs baseline: 5.3927x; 1.2078x over previous
//
#include <hip/hip_runtime.h>
#include <math.h>

#define NN 16384
#define H 128
#define CODE 1024

typedef __attribute__((ext_vector_type(8))) short short8;
typedef __attribute__((ext_vector_type(4))) float f32x4;

// ---- ws layout (bytes) ----
#define OFF_WIN   0u            // [128][1024] bf16, stride 2048
#define OFF_WOUT  262144u       // [1024][128] bf16, stride 256
#define OFF_P     524288u       // 4 x [256][128] bf16, stride 256 (65536 each)
#define OFF_N1    786432u       // 4 x [128][256] bf16, stride 512 (65536 each)
#define OFF_N2    1048576u      // 4 x [128][128] bf16, stride 256 (32768 each)
#define OFF_W2    1179648u      // 4 x 34816 (eW2^T bf16, 272-stride, edge kernel)
#define OFF_F     1318912u      // float area
#define OFF_H     (OFF_F)                    // h   fp32  8388608
#define OFF_HN    (OFF_H + 8388608u)         // hn  fp32  8388608
#define OFF_PBUF  (OFF_HN + 8388608u)        // P   fp32  16777216
#define OFF_AGGB  (OFF_PBUF + 16777216u)     // agg bf16  4194304
#define OFF_DEGI  (OFF_AGGB + 4194304u)      // deginv    65536
#define OFF_RPTR  (OFF_DEGI + 65536u)        // rowptr    65540

__device__ __forceinline__ float silu(float x) { return x / (1.0f + __expf(-x)); }

__device__ __forceinline__ unsigned short f2bf(float f) {
    unsigned int u = __float_as_uint(f);
    u = (u + 0x7FFFu + ((u >> 16) & 1u)) >> 16;
    return (unsigned short)u;
}

// 8 consecutive fp32 -> bf16 fragment
__device__ __forceinline__ short8 cvtfrag(const float* p) {
    float4 a = *(const float4*)p;
    float4 b = *(const float4*)(p + 4);
    short8 r;
    r[0] = (short)f2bf(a.x); r[1] = (short)f2bf(a.y); r[2] = (short)f2bf(a.z); r[3] = (short)f2bf(a.w);
    r[4] = (short)f2bf(b.x); r[5] = (short)f2bf(b.y); r[6] = (short)f2bf(b.z); r[7] = (short)f2bf(b.w);
    return r;
}

// ---------------- graph preprocessing ----------------
__global__ void k_rowptr(const int* __restrict__ rows, int E,
                         int* __restrict__ rowptr, float* __restrict__ deginv) {
    int n = blockIdx.x * blockDim.x + threadIdx.x;
    if (n > NN) return;
    int lo = 0, hi = E;
    while (lo < hi) { int mid = (lo + hi) >> 1; if (rows[mid] < n) lo = mid + 1; else hi = mid; }
    rowptr[n] = lo;
    if (n < NN) {
        int lo2 = lo, hi2 = E;
        while (lo2 < hi2) { int mid = (lo2 + hi2) >> 1; if (rows[mid] < n + 1) lo2 = mid + 1; else hi2 = mid; }
        int d = lo2 - lo; if (d < 1) d = 1;
        deginv[n] = 1.0f / (float)d;
    }
}

// eW2^T bf16 image (row n = output col, 272B padded stride) for edge kernel LDS staging
__global__ void k_prepw2(const float* __restrict__ eW2, char* __restrict__ w2img) {
    int t = blockIdx.x * 256 + threadIdx.x;
    if (t >= 4 * 128 * 128) return;
    int l = t >> 14, r = t & 16383;
    int k = r >> 7, n = r & 127;
    float v = eW2[l * 16384 + k * 128 + n];
    *(unsigned short*)(w2img + (size_t)l * 34816 + n * 272 + 2 * k) = f2bf(v);
}

// transposed bf16 weight images for all dense GEMMs
__global__ void k_prep(const float* __restrict__ W_in, const float* __restrict__ W_out,
                       const float* __restrict__ eW1, const float* __restrict__ nW1,
                       const float* __restrict__ nW2, char* __restrict__ base) {
    int t = blockIdx.x * 256 + threadIdx.x;
    if (t < 131072) {               // imgWin[n][k] = W_in[k][n]
        int n = t >> 10, k = t & 1023;
        *(unsigned short*)(base + OFF_WIN + n * 2048 + k * 2) = f2bf(W_in[k * 128 + n]);
        return;
    }
    t -= 131072;
    if (t < 131072) {               // imgWout[n][k] = W_out[k][n]
        int n = t >> 7, k = t & 127;
        *(unsigned short*)(base + OFF_WOUT + n * 256 + k * 2) = f2bf(W_out[k * 1024 + n]);
        return;
    }
    t -= 131072;
    if (t < 131072) {               // imgP[l][jj][k]
        int l = t >> 15, r = t & 32767;
        int jj = r >> 7, k = r & 127;
        const float* W = eW1 + (size_t)l * 257 * 128;
        float v = (jj < 128) ? W[k * 128 + jj] : W[(128 + k) * 128 + (jj - 128)];
        *(unsigned short*)(base + OFF_P + (size_t)l * 65536 + jj * 256 + k * 2) = f2bf(v);
        return;
    }
    t -= 131072;
    if (t < 131072) {               // imgN1[l][n][k] = nW1[l][k][n], k<256
        int l = t >> 15, r = t & 32767;
        int n = r >> 8, k = r & 255;
        *(unsigned short*)(base + OFF_N1 + (size_t)l * 65536 + n * 512 + k * 2) =
            f2bf(nW1[(size_t)l * 256 * 128 + k * 128 + n]);
        return;
    }
    t -= 131072;
    if (t < 65536) {                // imgN2[l][n][k] = nW2[l][k][n]
        int l = t >> 14, r = t & 16383;
        int n = r >> 7, k = r & 127;
        *(unsigned short*)(base + OFF_N2 + (size_t)l * 32768 + n * 256 + k * 2) =
            f2bf(nW2[(size_t)l * 128 * 128 + k * 128 + n]);
    }
}

// ---------------- h = y @ W_in + b_in (MFMA) ----------------
__global__ __launch_bounds__(256) void k_in_mfma(const float* __restrict__ y,
                                                 const char* __restrict__ imgWin,
                                                 const float* __restrict__ bi,
                                                 float* __restrict__ h) {
    int tid = threadIdx.x, w = tid >> 6, lane = tid & 63;
    int l15 = lane & 15, kg = lane >> 4;
    int m0 = blockIdx.x * 64 + w * 16;
    const float* yr = y + (size_t)(m0 + l15) * CODE;
    f32x4 acc[8];
#pragma unroll
    for (int nt = 0; nt < 8; nt++) { f32x4 z = {0.f,0.f,0.f,0.f}; acc[nt] = z; }
#pragma unroll 4
    for (int ks = 0; ks < 32; ks++) {
        short8 a = cvtfrag(yr + ks * 32 + kg * 8);
        const char* bp = imgWin + ks * 64 + kg * 16;
#pragma unroll
        for (int nt = 0; nt < 8; nt++) {
            short8 b = *(const short8*)(bp + (nt * 16 + l15) * 2048);
            acc[nt] = __builtin_amdgcn_mfma_f32_16x16x32_bf16(a, b, acc[nt], 0, 0, 0);
        }
    }
#pragma unroll
    for (int nt = 0; nt < 8; nt++) {
        int cc = nt * 16 + l15;
        float bb = bi[cc];
#pragma unroll
        for (int r = 0; r < 4; r++)
            h[(size_t)(m0 + kg * 4 + r) * H + cc] = acc[nt][r] + bb;
    }
}

// ---------------- LayerNorm (fp32, unchanged) ----------------
__global__ void k_ln(const float* __restrict__ h, const float* __restrict__ g,
                     const float* __restrict__ b, float* __restrict__ hn) {
    int wave = threadIdx.x >> 6, lane = threadIdx.x & 63;
    int n = blockIdx.x * 4 + wave;
    const float* hr = h + (size_t)n * H;
    float x0 = hr[lane], x1 = hr[lane + 64];
    float s = x0 + x1;
#pragma unroll
    for (int off = 32; off; off >>= 1) s += __shfl_xor(s, off);
    float mu = s * (1.0f / 128.0f);
    float d0 = x0 - mu, d1 = x1 - mu;
    float v = d0 * d0 + d1 * d1;
#pragma unroll
    for (int off = 32; off; off >>= 1) v += __shfl_xor(v, off);
    float rs = rsqrtf(v * (1.0f / 128.0f) + 1e-5f);
    float* o = hn + (size_t)n * H;
    o[lane]      = d0 * rs * g[lane]      + b[lane];
    o[lane + 64] = d1 * rs * g[lane + 64] + b[lane + 64];
}

// ---------------- P = hn @ [W1a|W1b] (+b1 on upper half) (MFMA) ----------------
__global__ __launch_bounds__(256) void k_P_mfma(const float* __restrict__ hn,
                                                const char* __restrict__ imgP,
                                                const float* __restrict__ b1,
                                                float* __restrict__ P) {
    int bid = blockIdx.x;
    int rowblk = bid >> 1, nc = bid & 1;
    int tid = threadIdx.x, w = tid >> 6, lane = tid & 63;
    int l15 = lane & 15, kg = lane >> 4;
    int m0 = rowblk * 64 + w * 16;
    const float* hr = hn + (size_t)(m0 + l15) * H;
    short8 a[4];
#pragma unroll
    for (int ks = 0; ks < 4; ks++) a[ks] = cvtfrag(hr + ks * 32 + kg * 8);
    f32x4 acc[8];
#pragma unroll
    for (int nt = 0; nt < 8; nt++) { f32x4 z = {0.f,0.f,0.f,0.f}; acc[nt] = z; }
#pragma unroll
    for (int ks = 0; ks < 4; ks++) {
        const char* bp = imgP + (size_t)(nc * 128) * 256 + ks * 64 + kg * 16;
#pragma unroll
        for (int nt = 0; nt < 8; nt++) {
            short8 b = *(const short8*)(bp + (nt * 16 + l15) * 256);
            acc[nt] = __builtin_amdgcn_mfma_f32_16x16x32_bf16(a[ks], b, acc[nt], 0, 0, 0);
        }
    }
#pragma unroll
    for (int nt = 0; nt < 8; nt++) {
        int jj = nc * 128 + nt * 16 + l15;
        float add = nc ? b1[nt * 16 + l15] : 0.0f;
#pragma unroll
        for (int r = 0; r < 4; r++)
            P[(size_t)(m0 + kg * 4 + r) * 256 + jj] = acc[nt][r] + add;
    }
}

// ---------------- fused edge MLP + aggregation (MFMA), agg out as bf16 ----------------
__global__ __launch_bounds__(128) void k_edge_mfma(
        const float* __restrict__ P, const float* __restrict__ gc,
        const int* __restrict__ cols, const int* __restrict__ rowptr,
        const float* __restrict__ deginv, const char* __restrict__ w2img,
        const float* __restrict__ w256, const float* __restrict__ b2,
        char* __restrict__ aggb) {
    __shared__ __align__(16) char sBt[128 * 272];
    __shared__ __align__(16) char sA[2][32 * 272];
    __shared__ int   s_sc[2][32];
    __shared__ float s_sd[2][32];

    int tid = threadIdx.x;
    int wave = tid >> 6, lane = tid & 63;
    int n = blockIdx.x * 2 + wave;

    {
        const uint4* src = (const uint4*)w2img;
        uint4* dst = (uint4*)sBt;
        for (int i = tid; i < 128 * 272 / 16; i += 128) dst[i] = src[i];
    }

    int e0 = rowptr[n];
    int deg = rowptr[n + 1] - e0;

    if (lane < 32) {
        bool v = lane < deg;
        int c = v ? cols[e0 + lane] : n;
        s_sc[wave][lane] = c;
        float dx = gc[3 * n] - gc[3 * c];
        float dy = gc[3 * n + 1] - gc[3 * c + 1];
        float dz = gc[3 * n + 2] - gc[3 * c + 2];
        s_sd[wave][lane] = v ? sqrtf(dx * dx + dy * dy + dz * dz) : 0.0f;
    }

    int j0 = lane, j1 = lane + 64;
    float p2a = P[(size_t)n * 256 + 128 + j0];
    float p2b = P[(size_t)n * 256 + 128 + j1];
    float wa = w256[j0], wb = w256[j1];

#pragma unroll 8
    for (int e = 0; e < 32; e++) {
        int c = s_sc[wave][e];
        float d = s_sd[wave][e];
        float va = P[(size_t)c * 256 + j0] + p2a + d * wa;
        float vb = P[(size_t)c * 256 + j1] + p2b + d * wb;
        va = silu(va); vb = silu(vb);
        bool valid = e < deg;
        unsigned short ba = valid ? f2bf(va) : (unsigned short)0;
        unsigned short bb = valid ? f2bf(vb) : (unsigned short)0;
        *(unsigned short*)(&sA[wave][e * 272 + 2 * j0]) = ba;
        *(unsigned short*)(&sA[wave][e * 272 + 2 * j1]) = bb;
    }
    __syncthreads();

    int r15 = lane & 15;
    int krow = lane >> 4;
    f32x4 acc[2][8];
#pragma unroll
    for (int mt = 0; mt < 2; mt++)
#pragma unroll
        for (int nt = 0; nt < 8; nt++) { f32x4 z = {0.f,0.f,0.f,0.f}; acc[mt][nt] = z; }

#pragma unroll
    for (int ks = 0; ks < 4; ks++) {
        int kb = ks * 64 + krow * 16;
        short8 a0 = *(const short8*)(&sA[wave][r15 * 272 + kb]);
        short8 a1 = *(const short8*)(&sA[wave][(r15 + 16) * 272 + kb]);
#pragma unroll
        for (int nt = 0; nt < 8; nt++) {
            short8 bfr = *(const short8*)(&sBt[(nt * 16 + r15) * 272 + kb]);
            acc[0][nt] = __builtin_amdgcn_mfma_f32_16x16x32_bf16(a0, bfr, acc[0][nt], 0, 0, 0);
            acc[1][nt] = __builtin_amdgcn_mfma_f32_16x16x32_bf16(a1, bfr, acc[1][nt], 0, 0, 0);
        }
    }

    float dinv = deginv[n];
    float b2v[8];
#pragma unroll
    for (int nt = 0; nt < 8; nt++) b2v[nt] = b2[nt * 16 + r15];

#pragma unroll
    for (int nt = 0; nt < 8; nt++) {
        float s = 0.0f;
#pragma unroll
        for (int mt = 0; mt < 2; mt++) {
            int rbase = krow * 4 + mt * 16;
#pragma unroll
            for (int r = 0; r < 4; r++) {
                float v = acc[mt][nt][r] + b2v[nt];
                v = silu(v);
                s += ((rbase + r) < deg) ? v : 0.0f;
            }
        }
        s += __shfl_xor(s, 16);
        s += __shfl_xor(s, 32);
        if (lane < 16)
            *(unsigned short*)(aggb + (size_t)n * 256 + (nt * 16 + lane) * 2) = f2bf(s * dinv);
    }
}

// ---------------- fused node MLP + residual (MFMA x2) ----------------
__global__ __launch_bounds__(256) void k_node_mfma(
        const float* __restrict__ hn, const char* __restrict__ aggb,
        const char* __restrict__ imgN1, const float* __restrict__ nb1,
        const char* __restrict__ imgN2, const float* __restrict__ nb2,
        float* __restrict__ h) {
    __shared__ __align__(16) char sM[4][16 * 272];
    int tid = threadIdx.x, w = tid >> 6, lane = tid & 63;
    int l15 = lane & 15, kg = lane >> 4;
    int m0 = blockIdx.x * 64 + w * 16;
    const float* hr = hn + (size_t)(m0 + l15) * H;
    const char*  ar = aggb + (size_t)(m0 + l15) * 256;

    f32x4 acc[8];
#pragma unroll
    for (int nt = 0; nt < 8; nt++) { f32x4 z = {0.f,0.f,0.f,0.f}; acc[nt] = z; }
#pragma unroll
    for (int ks = 0; ks < 8; ks++) {
        short8 a;
        if (ks < 4) a = cvtfrag(hr + ks * 32 + kg * 8);
        else        a = *(const short8*)(ar + (ks - 4) * 64 + kg * 16);
        const char* bp = imgN1 + ks * 64 + kg * 16;
#pragma unroll
        for (int nt = 0; nt < 8; nt++) {
            short8 b = *(const short8*)(bp + (nt * 16 + l15) * 512);
            acc[nt] = __builtin_amdgcn_mfma_f32_16x16x32_bf16(a, b, acc[nt], 0, 0, 0);
        }
    }
    // silu + bias -> per-wave LDS tile (bf16) for re-fragmentation
#pragma unroll
    for (int nt = 0; nt < 8; nt++) {
        int cc = nt * 16 + l15;
        float bb = nb1[cc];
#pragma unroll
        for (int r = 0; r < 4; r++) {
            float v = silu(acc[nt][r] + bb);
            *(unsigned short*)(&sM[w][(kg * 4 + r) * 272 + cc * 2]) = f2bf(v);
        }
    }
    // GEMM2: m @ nW2  (wave-private LDS, no barrier needed)
    f32x4 acc2[8];
#pragma unroll
    for (int nt = 0; nt < 8; nt++) { f32x4 z = {0.f,0.f,0.f,0.f}; acc2[nt] = z; }
#pragma unroll
    for (int ks = 0; ks < 4; ks++) {
        short8 a = *(const short8*)(&sM[w][l15 * 272 + ks * 64 + kg * 16]);
        const char* bp = imgN2 + ks * 64 + kg * 16;
#pragma unroll
        for (int nt = 0; nt < 8; nt++) {
            short8 b = *(const short8*)(bp + (nt * 16 + l15) * 256);
            acc2[nt] = __builtin_amdgcn_mfma_f32_16x16x32_bf16(a, b, acc2[nt], 0, 0, 0);
        }
    }
#pragma unroll
    for (int nt = 0; nt < 8; nt++) {
        int cc = nt * 16 + l15;
        float bb = nb2[cc];
#pragma unroll
        for (int r = 0; r < 4; r++) {
            size_t idx = (size_t)(m0 + kg * 4 + r) * H + cc;
            h[idx] = hn[idx] + acc2[nt][r] + bb;
        }
    }
}

// ---------------- out = h @ W_out + b_out (MFMA, N-parallel) ----------------
__global__ __launch_bounds__(256) void k_out_mfma(const float* __restrict__ h,
                                                  const char* __restrict__ imgWout,
                                                  const float* __restrict__ bo,
                                                  float* __restrict__ out) {
    int bid = blockIdx.x;
    int rowblk = bid >> 3, nc = bid & 7;
    int tid = threadIdx.x, w = tid >> 6, lane = tid & 63;
    int l15 = lane & 15, kg = lane >> 4;
    int m0 = rowblk * 64 + w * 16;
    const float* hr = h + (size_t)(m0 + l15) * H;
    short8 a[4];
#pragma unroll
    for (int ks = 0; ks < 4; ks++) a[ks] = cvtfrag(hr + ks * 32 + kg * 8);
    f32x4 acc[8];
#pragma unroll
    for (int nt = 0; nt < 8; nt++) { f32x4 z = {0.f,0.f,0.f,0.f}; acc[nt] = z; }
#pragma unroll
    for (int ks = 0; ks < 4; ks++) {
        const char* bp = imgWout + (size_t)(nc * 128) * 256 + ks * 64 + kg * 16;
#pragma unroll
        for (int nt = 0; nt < 8; nt++) {
            short8 b = *(const short8*)(bp + (nt * 16 + l15) * 256);
            acc[nt] = __builtin_amdgcn_mfma_f32_16x16x32_bf16(a[ks], b, acc[nt], 0, 0, 0);
        }
    }
#pragma unroll
    for (int nt = 0; nt < 8; nt++) {
        int cc = nc * 128 + nt * 16 + l15;
        float bb = bo[cc];
#pragma unroll
        for (int r = 0; r < 4; r++)
            out[(size_t)(m0 + kg * 4 + r) * 1024 + cc] = acc[nt][r] + bb;
    }
}

extern "C" void kernel_launch(void* const* d_in, const int* in_sizes, int n_in,
                              void* d_out, int out_size, void* d_ws, size_t ws_size,
                              hipStream_t stream) {
    const float* y     = (const float*)d_in[0];
    const float* gc    = (const float*)d_in[1];
    const int*   ei    = (const int*)  d_in[2];
    const float* W_in  = (const float*)d_in[3];
    const float* b_in  = (const float*)d_in[4];
    const float* ln_g  = (const float*)d_in[5];
    const float* ln_b  = (const float*)d_in[6];
    const float* eW1   = (const float*)d_in[7];
    const float* eb1   = (const float*)d_in[8];
    const float* eW2   = (const float*)d_in[9];
    const float* eb2   = (const float*)d_in[10];
    const float* nW1   = (const float*)d_in[11];
    const float* nb1   = (const float*)d_in[12];
    const float* nW2   = (const float*)d_in[13];
    const float* nb2   = (const float*)d_in[14];
    const float* W_out = (const float*)d_in[15];
    const float* b_out = (const float*)d_in[16];

    int E = in_sizes[2] / 2;
    const int* rows = ei;
    const int* cols = ei + E;

    char* wsb = (char*)d_ws;
    float* h      = (float*)(wsb + OFF_H);
    float* hn     = (float*)(wsb + OFF_HN);
    float* P      = (float*)(wsb + OFF_PBUF);
    char*  aggb   = wsb + OFF_AGGB;
    float* deginv = (float*)(wsb + OFF_DEGI);
    int*   rowptr = (int*)(wsb + OFF_RPTR);

    k_prepw2<<<(4 * 128 * 128 + 255) / 256, 256, 0, stream>>>(eW2, wsb + OFF_W2);
    k_prep<<<589824 / 256, 256, 0, stream>>>(W_in, W_out, eW1, nW1, nW2, wsb);
    k_rowptr<<<(NN + 1 + 255) / 256, 256, 0, stream>>>(rows, E, rowptr, deginv);
    k_in_mfma<<<NN / 64, 256, 0, stream>>>(y, wsb + OFF_WIN, b_in, h);
    for (int l = 0; l < 4; ++l) {
        k_ln<<<NN / 4, 256, 0, stream>>>(h, ln_g + l * H, ln_b + l * H, hn);
        k_P_mfma<<<NN / 64 * 2, 256, 0, stream>>>(hn, wsb + OFF_P + (size_t)l * 65536,
                                                  eb1 + l * H, P);
        k_edge_mfma<<<NN / 2, 128, 0, stream>>>(P, gc, cols, rowptr, deginv,
                                                wsb + OFF_W2 + (size_t)l * 34816,
                                                eW1 + (size_t)l * 257 * H + 256 * H,
                                                eb2 + l * H, aggb);
        k_node_mfma<<<NN / 64, 256, 0, stream>>>(hn, aggb,
                                                 wsb + OFF_N1 + (size_t)l * 65536, nb1 + l * H,
                                                 wsb + OFF_N2 + (size_t)l * 32768, nb2 + l * H, h);
    }
    k_out_mfma<<<NN / 64 * 8, 256, 0, stream>>>(h, wsb + OFF_WOUT, b_out, (float*)d_out);
}

// Round 4
// 831.946 us; speedup vs baseline: 5.9210x; 1.0980x over previous
//
#include <hip/hip_runtime.h>
#include <math.h>

#define NN 16384
#define H 128
#define CODE 1024

typedef __attribute__((ext_vector_type(8))) short short8;
typedef __attribute__((ext_vector_type(4))) float f32x4;

// ---- ws layout (bytes) ----
#define OFF_WIN   0u            // [128][1024] bf16, stride 2048
#define OFF_WOUT  262144u       // [1024][128] bf16, stride 256
#define OFF_P     524288u       // 4 x [256][128] bf16, stride 256 (65536 each)
#define OFF_N1    786432u       // 4 x [128][256] bf16, stride 512 (65536 each)
#define OFF_N2    1048576u      // 4 x [128][128] bf16, stride 256 (32768 each)
#define OFF_W2    1179648u      // 4 x [128][128] bf16 eW2^T, stride 256 (32768 each)
#define OFF_F     1318912u      // float area
#define OFF_H     (OFF_F)                    // h   fp32  8388608
#define OFF_HN    (OFF_H + 8388608u)         // hn  fp32  8388608
#define OFF_PBUF  (OFF_HN + 8388608u)        // P   fp32  16777216
#define OFF_AGGB  (OFF_PBUF + 16777216u)     // agg bf16  4194304
#define OFF_DEGI  (OFF_AGGB + 4194304u)      // deginv    65536
#define OFF_RPTR  (OFF_DEGI + 65536u)        // rowptr    65540

__device__ __forceinline__ float silu(float x) { return x / (1.0f + __expf(-x)); }

__device__ __forceinline__ unsigned short f2bf(float f) {
    unsigned int u = __float_as_uint(f);
    u = (u + 0x7FFFu + ((u >> 16) & 1u)) >> 16;
    return (unsigned short)u;
}

__device__ __forceinline__ short8 cvtfrag(const float* p) {
    float4 a = *(const float4*)p;
    float4 b = *(const float4*)(p + 4);
    short8 r;
    r[0] = (short)f2bf(a.x); r[1] = (short)f2bf(a.y); r[2] = (short)f2bf(a.z); r[3] = (short)f2bf(a.w);
    r[4] = (short)f2bf(b.x); r[5] = (short)f2bf(b.y); r[6] = (short)f2bf(b.z); r[7] = (short)f2bf(b.w);
    return r;
}

// ---------------- graph preprocessing ----------------
__global__ void k_rowptr(const int* __restrict__ rows, int E,
                         int* __restrict__ rowptr, float* __restrict__ deginv) {
    int n = blockIdx.x * blockDim.x + threadIdx.x;
    if (n > NN) return;
    int lo = 0, hi = E;
    while (lo < hi) { int mid = (lo + hi) >> 1; if (rows[mid] < n) lo = mid + 1; else hi = mid; }
    rowptr[n] = lo;
    if (n < NN) {
        int lo2 = lo, hi2 = E;
        while (lo2 < hi2) { int mid = (lo2 + hi2) >> 1; if (rows[mid] < n + 1) lo2 = mid + 1; else hi2 = mid; }
        int d = lo2 - lo; if (d < 1) d = 1;
        deginv[n] = 1.0f / (float)d;
    }
}

// transposed bf16 weight images for all GEMMs (incl. eW2^T at stride 256)
__global__ void k_prep(const float* __restrict__ W_in, const float* __restrict__ W_out,
                       const float* __restrict__ eW1, const float* __restrict__ nW1,
                       const float* __restrict__ nW2, const float* __restrict__ eW2,
                       char* __restrict__ base) {
    int t = blockIdx.x * 256 + threadIdx.x;
    if (t < 131072) {               // imgWin[n][k] = W_in[k][n]
        int n = t >> 10, k = t & 1023;
        *(unsigned short*)(base + OFF_WIN + n * 2048 + k * 2) = f2bf(W_in[k * 128 + n]);
        return;
    }
    t -= 131072;
    if (t < 131072) {               // imgWout[n][k] = W_out[k][n]
        int n = t >> 7, k = t & 127;
        *(unsigned short*)(base + OFF_WOUT + n * 256 + k * 2) = f2bf(W_out[k * 1024 + n]);
        return;
    }
    t -= 131072;
    if (t < 131072) {               // imgP[l][jj][k]
        int l = t >> 15, r = t & 32767;
        int jj = r >> 7, k = r & 127;
        const float* W = eW1 + (size_t)l * 257 * 128;
        float v = (jj < 128) ? W[k * 128 + jj] : W[(128 + k) * 128 + (jj - 128)];
        *(unsigned short*)(base + OFF_P + (size_t)l * 65536 + jj * 256 + k * 2) = f2bf(v);
        return;
    }
    t -= 131072;
    if (t < 131072) {               // imgN1[l][n][k] = nW1[l][k][n]
        int l = t >> 15, r = t & 32767;
        int n = r >> 8, k = r & 255;
        *(unsigned short*)(base + OFF_N1 + (size_t)l * 65536 + n * 512 + k * 2) =
            f2bf(nW1[(size_t)l * 256 * 128 + k * 128 + n]);
        return;
    }
    t -= 131072;
    if (t < 65536) {                // imgN2[l][n][k] = nW2[l][k][n]
        int l = t >> 14, r = t & 16383;
        int n = r >> 7, k = r & 127;
        *(unsigned short*)(base + OFF_N2 + (size_t)l * 32768 + n * 256 + k * 2) =
            f2bf(nW2[(size_t)l * 128 * 128 + k * 128 + n]);
        return;
    }
    t -= 65536;
    if (t < 65536) {                // imgW2[l][n][k] = eW2[l][k][n]
        int l = t >> 14, r = t & 16383;
        int n = r >> 7, k = r & 127;
        *(unsigned short*)(base + OFF_W2 + (size_t)l * 32768 + n * 256 + k * 2) =
            f2bf(eW2[(size_t)l * 128 * 128 + k * 128 + n]);
    }
}

// ---------------- h = y @ W_in + b_in (MFMA) ----------------
__global__ __launch_bounds__(256) void k_in_mfma(const float* __restrict__ y,
                                                 const char* __restrict__ imgWin,
                                                 const float* __restrict__ bi,
                                                 float* __restrict__ h) {
    int tid = threadIdx.x, w = tid >> 6, lane = tid & 63;
    int l15 = lane & 15, kg = lane >> 4;
    int m0 = blockIdx.x * 64 + w * 16;
    const float* yr = y + (size_t)(m0 + l15) * CODE;
    f32x4 acc[8];
#pragma unroll
    for (int nt = 0; nt < 8; nt++) { f32x4 z = {0.f,0.f,0.f,0.f}; acc[nt] = z; }
#pragma unroll 4
    for (int ks = 0; ks < 32; ks++) {
        short8 a = cvtfrag(yr + ks * 32 + kg * 8);
        const char* bp = imgWin + ks * 64 + kg * 16;
#pragma unroll
        for (int nt = 0; nt < 8; nt++) {
            short8 b = *(const short8*)(bp + (nt * 16 + l15) * 2048);
            acc[nt] = __builtin_amdgcn_mfma_f32_16x16x32_bf16(a, b, acc[nt], 0, 0, 0);
        }
    }
#pragma unroll
    for (int nt = 0; nt < 8; nt++) {
        int cc = nt * 16 + l15;
        float bb = bi[cc];
#pragma unroll
        for (int r = 0; r < 4; r++)
            h[(size_t)(m0 + kg * 4 + r) * H + cc] = acc[nt][r] + bb;
    }
}

// ---------------- LayerNorm ----------------
__global__ void k_ln(const float* __restrict__ h, const float* __restrict__ g,
                     const float* __restrict__ b, float* __restrict__ hn) {
    int wave = threadIdx.x >> 6, lane = threadIdx.x & 63;
    int n = blockIdx.x * 4 + wave;
    const float* hr = h + (size_t)n * H;
    float x0 = hr[lane], x1 = hr[lane + 64];
    float s = x0 + x1;
#pragma unroll
    for (int off = 32; off; off >>= 1) s += __shfl_xor(s, off);
    float mu = s * (1.0f / 128.0f);
    float d0 = x0 - mu, d1 = x1 - mu;
    float v = d0 * d0 + d1 * d1;
#pragma unroll
    for (int off = 32; off; off >>= 1) v += __shfl_xor(v, off);
    float rs = rsqrtf(v * (1.0f / 128.0f) + 1e-5f);
    float* o = hn + (size_t)n * H;
    o[lane]      = d0 * rs * g[lane]      + b[lane];
    o[lane + 64] = d1 * rs * g[lane + 64] + b[lane + 64];
}

// ---------------- P = hn @ [W1a|W1b] (+b1 on upper half) (MFMA) ----------------
__global__ __launch_bounds__(256) void k_P_mfma(const float* __restrict__ hn,
                                                const char* __restrict__ imgP,
                                                const float* __restrict__ b1,
                                                float* __restrict__ P) {
    int bid = blockIdx.x;
    int rowblk = bid >> 1, nc = bid & 1;
    int tid = threadIdx.x, w = tid >> 6, lane = tid & 63;
    int l15 = lane & 15, kg = lane >> 4;
    int m0 = rowblk * 64 + w * 16;
    const float* hr = hn + (size_t)(m0 + l15) * H;
    short8 a[4];
#pragma unroll
    for (int ks = 0; ks < 4; ks++) a[ks] = cvtfrag(hr + ks * 32 + kg * 8);
    f32x4 acc[8];
#pragma unroll
    for (int nt = 0; nt < 8; nt++) { f32x4 z = {0.f,0.f,0.f,0.f}; acc[nt] = z; }
#pragma unroll
    for (int ks = 0; ks < 4; ks++) {
        const char* bp = imgP + (size_t)(nc * 128) * 256 + ks * 64 + kg * 16;
#pragma unroll
        for (int nt = 0; nt < 8; nt++) {
            short8 b = *(const short8*)(bp + (nt * 16 + l15) * 256);
            acc[nt] = __builtin_amdgcn_mfma_f32_16x16x32_bf16(a[ks], b, acc[nt], 0, 0, 0);
        }
    }
#pragma unroll
    for (int nt = 0; nt < 8; nt++) {
        int jj = nc * 128 + nt * 16 + l15;
        float add = nc ? b1[nt * 16 + l15] : 0.0f;
#pragma unroll
        for (int r = 0; r < 4; r++)
            P[(size_t)(m0 + kg * 4 + r) * 256 + jj] = acc[nt][r] + add;
    }
}

// ---------------- fused edge MLP + aggregation (MFMA), B direct from L2 ----------------
__global__ __launch_bounds__(128) void k_edge_mfma(
        const float* __restrict__ P, const float* __restrict__ gc,
        const int* __restrict__ cols, const int* __restrict__ rowptr,
        const float* __restrict__ deginv, const char* __restrict__ imgW2,
        const float* __restrict__ w256, const float* __restrict__ b2,
        char* __restrict__ aggb) {
    __shared__ __align__(16) char sA[2][32 * 272];   // 17.4 KB total -> high occupancy
    __shared__ int   s_sc[2][32];
    __shared__ float s_sd[2][32];

    int tid = threadIdx.x;
    int wave = tid >> 6, lane = tid & 63;
    int n = blockIdx.x * 2 + wave;

    int e0 = rowptr[n];
    int deg = rowptr[n + 1] - e0;

    if (lane < 32) {
        bool v = lane < deg;
        int c = v ? cols[e0 + lane] : n;
        s_sc[wave][lane] = c;
        float dx = gc[3 * n] - gc[3 * c];
        float dy = gc[3 * n + 1] - gc[3 * c + 1];
        float dz = gc[3 * n + 2] - gc[3 * c + 2];
        s_sd[wave][lane] = v ? sqrtf(dx * dx + dy * dy + dz * dz) : 0.0f;
    }

    int j0 = lane, j1 = lane + 64;
    float p2a = P[(size_t)n * 256 + 128 + j0];
    float p2b = P[(size_t)n * 256 + 128 + j1];
    float wa = w256[j0], wb = w256[j1];

#pragma unroll 8
    for (int e = 0; e < 32; e++) {
        int c = s_sc[wave][e];
        float d = s_sd[wave][e];
        float va = P[(size_t)c * 256 + j0] + p2a + d * wa;
        float vb = P[(size_t)c * 256 + j1] + p2b + d * wb;
        va = silu(va); vb = silu(vb);
        bool valid = e < deg;
        unsigned short ba = valid ? f2bf(va) : (unsigned short)0;
        unsigned short bb = valid ? f2bf(vb) : (unsigned short)0;
        *(unsigned short*)(&sA[wave][e * 272 + 2 * j0]) = ba;
        *(unsigned short*)(&sA[wave][e * 272 + 2 * j1]) = bb;
    }
    __syncthreads();

    int r15 = lane & 15;
    int krow = lane >> 4;
    f32x4 acc[2][8];
#pragma unroll
    for (int mt = 0; mt < 2; mt++)
#pragma unroll
        for (int nt = 0; nt < 8; nt++) { f32x4 z = {0.f,0.f,0.f,0.f}; acc[mt][nt] = z; }

#pragma unroll
    for (int ks = 0; ks < 4; ks++) {
        int kb = ks * 64 + krow * 16;
        short8 a0 = *(const short8*)(&sA[wave][r15 * 272 + kb]);
        short8 a1 = *(const short8*)(&sA[wave][(r15 + 16) * 272 + kb]);
        const char* bp = imgW2 + kb;
#pragma unroll
        for (int nt = 0; nt < 8; nt++) {
            short8 bfr = *(const short8*)(bp + (nt * 16 + r15) * 256);
            acc[0][nt] = __builtin_amdgcn_mfma_f32_16x16x32_bf16(a0, bfr, acc[0][nt], 0, 0, 0);
            acc[1][nt] = __builtin_amdgcn_mfma_f32_16x16x32_bf16(a1, bfr, acc[1][nt], 0, 0, 0);
        }
    }

    float dinv = deginv[n];
    float b2v[8];
#pragma unroll
    for (int nt = 0; nt < 8; nt++) b2v[nt] = b2[nt * 16 + r15];

#pragma unroll
    for (int nt = 0; nt < 8; nt++) {
        float s = 0.0f;
#pragma unroll
        for (int mt = 0; mt < 2; mt++) {
            int rbase = krow * 4 + mt * 16;
#pragma unroll
            for (int r = 0; r < 4; r++) {
                float v = acc[mt][nt][r] + b2v[nt];
                v = silu(v);
                s += ((rbase + r) < deg) ? v : 0.0f;
            }
        }
        s += __shfl_xor(s, 16);
        s += __shfl_xor(s, 32);
        if (lane < 16)
            *(unsigned short*)(aggb + (size_t)n * 256 + (nt * 16 + lane) * 2) = f2bf(s * dinv);
    }
}

// ---------------- fused node MLP + residual (MFMA x2) ----------------
__global__ __launch_bounds__(256) void k_node_mfma(
        const float* __restrict__ hn, const char* __restrict__ aggb,
        const char* __restrict__ imgN1, const float* __restrict__ nb1,
        const char* __restrict__ imgN2, const float* __restrict__ nb2,
        float* __restrict__ h) {
    __shared__ __align__(16) char sM[4][16 * 272];
    int tid = threadIdx.x, w = tid >> 6, lane = tid & 63;
    int l15 = lane & 15, kg = lane >> 4;
    int m0 = blockIdx.x * 64 + w * 16;
    const float* hr = hn + (size_t)(m0 + l15) * H;
    const char*  ar = aggb + (size_t)(m0 + l15) * 256;

    f32x4 acc[8];
#pragma unroll
    for (int nt = 0; nt < 8; nt++) { f32x4 z = {0.f,0.f,0.f,0.f}; acc[nt] = z; }
#pragma unroll
    for (int ks = 0; ks < 8; ks++) {
        short8 a;
        if (ks < 4) a = cvtfrag(hr + ks * 32 + kg * 8);
        else        a = *(const short8*)(ar + (ks - 4) * 64 + kg * 16);
        const char* bp = imgN1 + ks * 64 + kg * 16;
#pragma unroll
        for (int nt = 0; nt < 8; nt++) {
            short8 b = *(const short8*)(bp + (nt * 16 + l15) * 512);
            acc[nt] = __builtin_amdgcn_mfma_f32_16x16x32_bf16(a, b, acc[nt], 0, 0, 0);
        }
    }
#pragma unroll
    for (int nt = 0; nt < 8; nt++) {
        int cc = nt * 16 + l15;
        float bb = nb1[cc];
#pragma unroll
        for (int r = 0; r < 4; r++) {
            float v = silu(acc[nt][r] + bb);
            *(unsigned short*)(&sM[w][(kg * 4 + r) * 272 + cc * 2]) = f2bf(v);
        }
    }
    f32x4 acc2[8];
#pragma unroll
    for (int nt = 0; nt < 8; nt++) { f32x4 z = {0.f,0.f,0.f,0.f}; acc2[nt] = z; }
#pragma unroll
    for (int ks = 0; ks < 4; ks++) {
        short8 a = *(const short8*)(&sM[w][l15 * 272 + ks * 64 + kg * 16]);
        const char* bp = imgN2 + ks * 64 + kg * 16;
#pragma unroll
        for (int nt = 0; nt < 8; nt++) {
            short8 b = *(const short8*)(bp + (nt * 16 + l15) * 256);
            acc2[nt] = __builtin_amdgcn_mfma_f32_16x16x32_bf16(a, b, acc2[nt], 0, 0, 0);
        }
    }
#pragma unroll
    for (int nt = 0; nt < 8; nt++) {
        int cc = nt * 16 + l15;
        float bb = nb2[cc];
#pragma unroll
        for (int r = 0; r < 4; r++) {
            size_t idx = (size_t)(m0 + kg * 4 + r) * H + cc;
            h[idx] = hn[idx] + acc2[nt][r] + bb;
        }
    }
}

// ---------------- out = h @ W_out + b_out (MFMA, N-parallel) ----------------
__global__ __launch_bounds__(256) void k_out_mfma(const float* __restrict__ h,
                                                  const char* __restrict__ imgWout,
                                                  const float* __restrict__ bo,
                                                  float* __restrict__ out) {
    int bid = blockIdx.x;
    int rowblk = bid >> 3, nc = bid & 7;
    int tid = threadIdx.x, w = tid >> 6, lane = tid & 63;
    int l15 = lane & 15, kg = lane >> 4;
    int m0 = rowblk * 64 + w * 16;
    const float* hr = h + (size_t)(m0 + l15) * H;
    short8 a[4];
#pragma unroll
    for (int ks = 0; ks < 4; ks++) a[ks] = cvtfrag(hr + ks * 32 + kg * 8);
    f32x4 acc[8];
#pragma unroll
    for (int nt = 0; nt < 8; nt++) { f32x4 z = {0.f,0.f,0.f,0.f}; acc[nt] = z; }
#pragma unroll
    for (int ks = 0; ks < 4; ks++) {
        const char* bp = imgWout + (size_t)(nc * 128) * 256 + ks * 64 + kg * 16;
#pragma unroll
        for (int nt = 0; nt < 8; nt++) {
            short8 b = *(const short8*)(bp + (nt * 16 + l15) * 256);
            acc[nt] = __builtin_amdgcn_mfma_f32_16x16x32_bf16(a[ks], b, acc[nt], 0, 0, 0);
        }
    }
#pragma unroll
    for (int nt = 0; nt < 8; nt++) {
        int cc = nc * 128 + nt * 16 + l15;
        float bb = bo[cc];
#pragma unroll
        for (int r = 0; r < 4; r++)
            out[(size_t)(m0 + kg * 4 + r) * 1024 + cc] = acc[nt][r] + bb;
    }
}

extern "C" void kernel_launch(void* const* d_in, const int* in_sizes, int n_in,
                              void* d_out, int out_size, void* d_ws, size_t ws_size,
                              hipStream_t stream) {
    const float* y     = (const float*)d_in[0];
    const float* gc    = (const float*)d_in[1];
    const int*   ei    = (const int*)  d_in[2];
    const float* W_in  = (const float*)d_in[3];
    const float* b_in  = (const float*)d_in[4];
    const float* ln_g  = (const float*)d_in[5];
    const float* ln_b  = (const float*)d_in[6];
    const float* eW1   = (const float*)d_in[7];
    const float* eb1   = (const float*)d_in[8];
    const float* eW2   = (const float*)d_in[9];
    const float* eb2   = (const float*)d_in[10];
    const float* nW1   = (const float*)d_in[11];
    const float* nb1   = (const float*)d_in[12];
    const float* nW2   = (const float*)d_in[13];
    const float* nb2   = (const float*)d_in[14];
    const float* W_out = (const float*)d_in[15];
    const float* b_out = (const float*)d_in[16];

    int E = in_sizes[2] / 2;
    const int* rows = ei;
    const int* cols = ei + E;

    char* wsb = (char*)d_ws;
    float* h      = (float*)(wsb + OFF_H);
    float* hn     = (float*)(wsb + OFF_HN);
    float* P      = (float*)(wsb + OFF_PBUF);
    char*  aggb   = wsb + OFF_AGGB;
    float* deginv = (float*)(wsb + OFF_DEGI);
    int*   rowptr = (int*)(wsb + OFF_RPTR);

    k_prep<<<655360 / 256, 256, 0, stream>>>(W_in, W_out, eW1, nW1, nW2, eW2, wsb);
    k_rowptr<<<(NN + 1 + 255) / 256, 256, 0, stream>>>(rows, E, rowptr, deginv);
    k_in_mfma<<<NN / 64, 256, 0, stream>>>(y, wsb + OFF_WIN, b_in, h);
    for (int l = 0; l < 4; ++l) {
        k_ln<<<NN / 4, 256, 0, stream>>>(h, ln_g + l * H, ln_b + l * H, hn);
        k_P_mfma<<<NN / 64 * 2, 256, 0, stream>>>(hn, wsb + OFF_P + (size_t)l * 65536,
                                                  eb1 + l * H, P);
        k_edge_mfma<<<NN / 2, 128, 0, stream>>>(P, gc, cols, rowptr, deginv,
                                                wsb + OFF_W2 + (size_t)l * 32768,
                                                eW1 + (size_t)l * 257 * H + 256 * H,
                                                eb2 + l * H, aggb);
        k_node_mfma<<<NN / 64, 256, 0, stream>>>(hn, aggb,
                                                 wsb + OFF_N1 + (size_t)l * 65536, nb1 + l * H,
                                                 wsb + OFF_N2 + (size_t)l * 32768, nb2 + l * H, h);
    }
    k_out_mfma<<<NN / 64 * 8, 256, 0, stream>>>(h, wsb + OFF_WOUT, b_out, (float*)d_out);
}

// Round 5
// 815.664 us; speedup vs baseline: 6.0392x; 1.0200x over previous
//
#include <hip/hip_runtime.h>
#include <math.h>

#define NN 16384
#define H 128
#define CODE 1024

typedef __attribute__((ext_vector_type(8))) short short8;
typedef __attribute__((ext_vector_type(4))) float f32x4;

// ---- ws layout (bytes) ----
#define OFF_WIN   0u            // [128][1024] bf16, stride 2048
#define OFF_WOUT  262144u       // [1024][128] bf16, stride 256
#define OFF_P     524288u       // 4 x [256][128] bf16, stride 256
#define OFF_N1    786432u       // 4 x [128][256] bf16, stride 512
#define OFF_N2    1048576u      // 4 x [128][128] bf16, stride 256
#define OFF_W2    1179648u      // 4 x [128][128] bf16 eW2^T, stride 256
#define OFF_H     1318912u                   // h   fp32  8388608
#define OFF_HN    (OFF_H + 8388608u)         // hn  fp32  8388608
#define OFF_PBUF  (OFF_HN + 8388608u)        // P   fp32  16777216
#define OFF_AGGB  (OFF_PBUF + 16777216u)     // agg bf16  4194304
#define OFF_DEGI  (OFF_AGGB + 4194304u)      // deginv    65536
#define OFF_RPTR  (OFF_DEGI + 65536u)        // rowptr    (NN+1)*4
#define OFF_DIST  (OFF_RPTR + 66048u)        // dist fp32 E*4 (<=1298432)
#define OFF_M1    (OFF_DIST + 1298432u)      // m1 bf16 (Ec+32)*128, chunked

__device__ __forceinline__ float silu(float x) { return x / (1.0f + __expf(-x)); }

__device__ __forceinline__ unsigned short f2bf(float f) {
    unsigned int u = __float_as_uint(f);
    u = (u + 0x7FFFu + ((u >> 16) & 1u)) >> 16;
    return (unsigned short)u;
}

__device__ __forceinline__ short8 cvtfrag(const float* p) {
    float4 a = *(const float4*)p;
    float4 b = *(const float4*)(p + 4);
    short8 r;
    r[0] = (short)f2bf(a.x); r[1] = (short)f2bf(a.y); r[2] = (short)f2bf(a.z); r[3] = (short)f2bf(a.w);
    r[4] = (short)f2bf(b.x); r[5] = (short)f2bf(b.y); r[6] = (short)f2bf(b.z); r[7] = (short)f2bf(b.w);
    return r;
}

// ---------------- graph preprocessing ----------------
__global__ void k_rowptr(const int* __restrict__ rows, int E,
                         int* __restrict__ rowptr, float* __restrict__ deginv) {
    int n = blockIdx.x * blockDim.x + threadIdx.x;
    if (n > NN) return;
    int lo = 0, hi = E;
    while (lo < hi) { int mid = (lo + hi) >> 1; if (rows[mid] < n) lo = mid + 1; else hi = mid; }
    rowptr[n] = lo;
    if (n < NN) {
        int lo2 = lo, hi2 = E;
        while (lo2 < hi2) { int mid = (lo2 + hi2) >> 1; if (rows[mid] < n + 1) lo2 = mid + 1; else hi2 = mid; }
        int d = lo2 - lo; if (d < 1) d = 1;
        deginv[n] = 1.0f / (float)d;
    }
}

__global__ void k_dist(const int* __restrict__ rows, const int* __restrict__ cols,
                       const float* __restrict__ gc, int E, float* __restrict__ dist) {
    int e = blockIdx.x * 256 + threadIdx.x;
    if (e >= E) return;
    int r = rows[e], c = cols[e];
    float dx = gc[3 * r] - gc[3 * c];
    float dy = gc[3 * r + 1] - gc[3 * c + 1];
    float dz = gc[3 * r + 2] - gc[3 * c + 2];
    dist[e] = sqrtf(dx * dx + dy * dy + dz * dz);
}

// transposed bf16 weight images for all GEMMs
__global__ void k_prep(const float* __restrict__ W_in, const float* __restrict__ W_out,
                       const float* __restrict__ eW1, const float* __restrict__ nW1,
                       const float* __restrict__ nW2, const float* __restrict__ eW2,
                       char* __restrict__ base) {
    int t = blockIdx.x * 256 + threadIdx.x;
    if (t < 131072) {
        int n = t >> 10, k = t & 1023;
        *(unsigned short*)(base + OFF_WIN + n * 2048 + k * 2) = f2bf(W_in[k * 128 + n]);
        return;
    }
    t -= 131072;
    if (t < 131072) {
        int n = t >> 7, k = t & 127;
        *(unsigned short*)(base + OFF_WOUT + n * 256 + k * 2) = f2bf(W_out[k * 1024 + n]);
        return;
    }
    t -= 131072;
    if (t < 131072) {
        int l = t >> 15, r = t & 32767;
        int jj = r >> 7, k = r & 127;
        const float* W = eW1 + (size_t)l * 257 * 128;
        float v = (jj < 128) ? W[k * 128 + jj] : W[(128 + k) * 128 + (jj - 128)];
        *(unsigned short*)(base + OFF_P + (size_t)l * 65536 + jj * 256 + k * 2) = f2bf(v);
        return;
    }
    t -= 131072;
    if (t < 131072) {
        int l = t >> 15, r = t & 32767;
        int n = r >> 8, k = r & 255;
        *(unsigned short*)(base + OFF_N1 + (size_t)l * 65536 + n * 512 + k * 2) =
            f2bf(nW1[(size_t)l * 256 * 128 + k * 128 + n]);
        return;
    }
    t -= 131072;
    if (t < 65536) {
        int l = t >> 14, r = t & 16383;
        int n = r >> 7, k = r & 127;
        *(unsigned short*)(base + OFF_N2 + (size_t)l * 32768 + n * 256 + k * 2) =
            f2bf(nW2[(size_t)l * 128 * 128 + k * 128 + n]);
        return;
    }
    t -= 65536;
    if (t < 65536) {
        int l = t >> 14, r = t & 16383;
        int n = r >> 7, k = r & 127;
        *(unsigned short*)(base + OFF_W2 + (size_t)l * 32768 + n * 256 + k * 2) =
            f2bf(eW2[(size_t)l * 128 * 128 + k * 128 + n]);
    }
}

// ---------------- h = y @ W_in + b_in (MFMA) ----------------
__global__ __launch_bounds__(256) void k_in_mfma(const float* __restrict__ y,
                                                 const char* __restrict__ imgWin,
                                                 const float* __restrict__ bi,
                                                 float* __restrict__ h) {
    int tid = threadIdx.x, w = tid >> 6, lane = tid & 63;
    int l15 = lane & 15, kg = lane >> 4;
    int m0 = blockIdx.x * 64 + w * 16;
    const float* yr = y + (size_t)(m0 + l15) * CODE;
    f32x4 acc[8];
#pragma unroll
    for (int nt = 0; nt < 8; nt++) { f32x4 z = {0.f,0.f,0.f,0.f}; acc[nt] = z; }
#pragma unroll 4
    for (int ks = 0; ks < 32; ks++) {
        short8 a = cvtfrag(yr + ks * 32 + kg * 8);
        const char* bp = imgWin + ks * 64 + kg * 16;
#pragma unroll
        for (int nt = 0; nt < 8; nt++) {
            short8 b = *(const short8*)(bp + (nt * 16 + l15) * 2048);
            acc[nt] = __builtin_amdgcn_mfma_f32_16x16x32_bf16(a, b, acc[nt], 0, 0, 0);
        }
    }
#pragma unroll
    for (int nt = 0; nt < 8; nt++) {
        int cc = nt * 16 + l15;
        float bb = bi[cc];
#pragma unroll
        for (int r = 0; r < 4; r++)
            h[(size_t)(m0 + kg * 4 + r) * H + cc] = acc[nt][r] + bb;
    }
}

// ---------------- LayerNorm ----------------
__global__ void k_ln(const float* __restrict__ h, const float* __restrict__ g,
                     const float* __restrict__ b, float* __restrict__ hn) {
    int wave = threadIdx.x >> 6, lane = threadIdx.x & 63;
    int n = blockIdx.x * 4 + wave;
    const float* hr = h + (size_t)n * H;
    float x0 = hr[lane], x1 = hr[lane + 64];
    float s = x0 + x1;
#pragma unroll
    for (int off = 32; off; off >>= 1) s += __shfl_xor(s, off);
    float mu = s * (1.0f / 128.0f);
    float d0 = x0 - mu, d1 = x1 - mu;
    float v = d0 * d0 + d1 * d1;
#pragma unroll
    for (int off = 32; off; off >>= 1) v += __shfl_xor(v, off);
    float rs = rsqrtf(v * (1.0f / 128.0f) + 1e-5f);
    float* o = hn + (size_t)n * H;
    o[lane]      = d0 * rs * g[lane]      + b[lane];
    o[lane + 64] = d1 * rs * g[lane + 64] + b[lane + 64];
}

// ---------------- P = hn @ [W1a|W1b] (+b1 on upper half) (MFMA) ----------------
__global__ __launch_bounds__(256) void k_P_mfma(const float* __restrict__ hn,
                                                const char* __restrict__ imgP,
                                                const float* __restrict__ b1,
                                                float* __restrict__ P) {
    int bid = blockIdx.x;
    int rowblk = bid >> 1, nc = bid & 1;
    int tid = threadIdx.x, w = tid >> 6, lane = tid & 63;
    int l15 = lane & 15, kg = lane >> 4;
    int m0 = rowblk * 64 + w * 16;
    const float* hr = hn + (size_t)(m0 + l15) * H;
    short8 a[4];
#pragma unroll
    for (int ks = 0; ks < 4; ks++) a[ks] = cvtfrag(hr + ks * 32 + kg * 8);
    f32x4 acc[8];
#pragma unroll
    for (int nt = 0; nt < 8; nt++) { f32x4 z = {0.f,0.f,0.f,0.f}; acc[nt] = z; }
#pragma unroll
    for (int ks = 0; ks < 4; ks++) {
        const char* bp = imgP + (size_t)(nc * 128) * 256 + ks * 64 + kg * 16;
#pragma unroll
        for (int nt = 0; nt < 8; nt++) {
            short8 b = *(const short8*)(bp + (nt * 16 + l15) * 256);
            acc[nt] = __builtin_amdgcn_mfma_f32_16x16x32_bf16(a[ks], b, acc[nt], 0, 0, 0);
        }
    }
#pragma unroll
    for (int nt = 0; nt < 8; nt++) {
        int jj = nc * 128 + nt * 16 + l15;
        float add = nc ? b1[nt * 16 + l15] : 0.0f;
#pragma unroll
        for (int r = 0; r < 4; r++)
            P[(size_t)(m0 + kg * 4 + r) * 256 + jj] = acc[nt][r] + add;
    }
}

// ---------------- m1 = silu(P1[col] + P2[row] + dist*w256), edge-parallel ----------------
__global__ __launch_bounds__(256) void k_m1(const float* __restrict__ P,
                                            const float* __restrict__ dist,
                                            const int* __restrict__ rows,
                                            const int* __restrict__ cols,
                                            const float* __restrict__ w256f,
                                            unsigned short* __restrict__ m1loc,
                                            int Ec, int ebase) {
    int idx = blockIdx.x * 256 + threadIdx.x;
    int el = idx >> 5, jq = idx & 31;
    if (el >= Ec) return;
    int e = ebase + el;
    int c = cols[e], n = rows[e];
    float d = dist[e];
    float4 p1 = *(const float4*)(P + (size_t)c * 256 + jq * 4);
    float4 p2 = *(const float4*)(P + (size_t)n * 256 + 128 + jq * 4);
    float4 w  = *(const float4*)(w256f + jq * 4);
    ushort4 o;
    o.x = f2bf(silu(p1.x + p2.x + d * w.x));
    o.y = f2bf(silu(p1.y + p2.y + d * w.y));
    o.z = f2bf(silu(p1.z + p2.z + d * w.z));
    o.w = f2bf(silu(p1.w + p2.w + d * w.w));
    *(ushort4*)(m1loc + (size_t)el * 128 + jq * 4) = o;
}

// ---------------- edge GEMM2 + silu + segmented sum (MFMA, no LDS) ----------------
__global__ __launch_bounds__(256) void k_edge2(const unsigned short* __restrict__ m1loc,
                                               const int* __restrict__ rowptr,
                                               const float* __restrict__ deginv,
                                               const char* __restrict__ imgW2,
                                               const float* __restrict__ b2,
                                               char* __restrict__ aggb,
                                               int n0, int ebase) {
    int tid = threadIdx.x, wave = tid >> 6, lane = tid & 63;
    int n = n0 + blockIdx.x * 4 + wave;
    int e0 = rowptr[n] - ebase;
    int deg = rowptr[n + 1] - ebase - e0;
    int r15 = lane & 15, kg = lane >> 4;

    const unsigned short* a0p = m1loc + (size_t)(e0 + r15) * 128;
    const unsigned short* a1p = a0p + 16 * 128;

    f32x4 acc0[8], acc1[8];
#pragma unroll
    for (int nt = 0; nt < 8; nt++) {
        f32x4 z = {0.f,0.f,0.f,0.f}; acc0[nt] = z; acc1[nt] = z;
    }
#pragma unroll
    for (int ks = 0; ks < 4; ks++) {
        short8 a0 = *(const short8*)(a0p + ks * 32 + kg * 8);
        short8 a1 = *(const short8*)(a1p + ks * 32 + kg * 8);
        const char* bp = imgW2 + ks * 64 + kg * 16;
#pragma unroll
        for (int nt = 0; nt < 8; nt++) {
            short8 b = *(const short8*)(bp + (nt * 16 + r15) * 256);
            acc0[nt] = __builtin_amdgcn_mfma_f32_16x16x32_bf16(a0, b, acc0[nt], 0, 0, 0);
            acc1[nt] = __builtin_amdgcn_mfma_f32_16x16x32_bf16(a1, b, acc1[nt], 0, 0, 0);
        }
    }

    float dinv = deginv[n];
#pragma unroll
    for (int nt = 0; nt < 8; nt++) {
        float bb = b2[nt * 16 + r15];
        float s = 0.0f;
        int rbase = kg * 4;
#pragma unroll
        for (int r = 0; r < 4; r++) {
            float v = silu(acc0[nt][r] + bb);
            s += ((rbase + r) < deg) ? v : 0.0f;
        }
#pragma unroll
        for (int r = 0; r < 4; r++) {
            float v = silu(acc1[nt][r] + bb);
            s += ((rbase + 16 + r) < deg) ? v : 0.0f;
        }
        s += __shfl_xor(s, 16);
        s += __shfl_xor(s, 32);
        if (lane < 16)
            *(unsigned short*)(aggb + (size_t)n * 256 + (nt * 16 + lane) * 2) = f2bf(s * dinv);
    }
}

// ---------------- fused node MLP + residual (MFMA x2) ----------------
__global__ __launch_bounds__(256) void k_node_mfma(
        const float* __restrict__ hn, const char* __restrict__ aggb,
        const char* __restrict__ imgN1, const float* __restrict__ nb1,
        const char* __restrict__ imgN2, const float* __restrict__ nb2,
        float* __restrict__ h) {
    __shared__ __align__(16) char sM[4][16 * 272];
    int tid = threadIdx.x, w = tid >> 6, lane = tid & 63;
    int l15 = lane & 15, kg = lane >> 4;
    int m0 = blockIdx.x * 64 + w * 16;
    const float* hr = hn + (size_t)(m0 + l15) * H;
    const char*  ar = aggb + (size_t)(m0 + l15) * 256;

    f32x4 acc[8];
#pragma unroll
    for (int nt = 0; nt < 8; nt++) { f32x4 z = {0.f,0.f,0.f,0.f}; acc[nt] = z; }
#pragma unroll
    for (int ks = 0; ks < 8; ks++) {
        short8 a;
        if (ks < 4) a = cvtfrag(hr + ks * 32 + kg * 8);
        else        a = *(const short8*)(ar + (ks - 4) * 64 + kg * 16);
        const char* bp = imgN1 + ks * 64 + kg * 16;
#pragma unroll
        for (int nt = 0; nt < 8; nt++) {
            short8 b = *(const short8*)(bp + (nt * 16 + l15) * 512);
            acc[nt] = __builtin_amdgcn_mfma_f32_16x16x32_bf16(a, b, acc[nt], 0, 0, 0);
        }
    }
#pragma unroll
    for (int nt = 0; nt < 8; nt++) {
        int cc = nt * 16 + l15;
        float bb = nb1[cc];
#pragma unroll
        for (int r = 0; r < 4; r++) {
            float v = silu(acc[nt][r] + bb);
            *(unsigned short*)(&sM[w][(kg * 4 + r) * 272 + cc * 2]) = f2bf(v);
        }
    }
    f32x4 acc2[8];
#pragma unroll
    for (int nt = 0; nt < 8; nt++) { f32x4 z = {0.f,0.f,0.f,0.f}; acc2[nt] = z; }
#pragma unroll
    for (int ks = 0; ks < 4; ks++) {
        short8 a = *(const short8*)(&sM[w][l15 * 272 + ks * 64 + kg * 16]);
        const char* bp = imgN2 + ks * 64 + kg * 16;
#pragma unroll
        for (int nt = 0; nt < 8; nt++) {
            short8 b = *(const short8*)(bp + (nt * 16 + l15) * 256);
            acc2[nt] = __builtin_amdgcn_mfma_f32_16x16x32_bf16(a, b, acc2[nt], 0, 0, 0);
        }
    }
#pragma unroll
    for (int nt = 0; nt < 8; nt++) {
        int cc = nt * 16 + l15;
        float bb = nb2[cc];
#pragma unroll
        for (int r = 0; r < 4; r++) {
            size_t idx = (size_t)(m0 + kg * 4 + r) * H + cc;
            h[idx] = hn[idx] + acc2[nt][r] + bb;
        }
    }
}

// ---------------- out = h @ W_out + b_out (MFMA, N-parallel) ----------------
__global__ __launch_bounds__(256) void k_out_mfma(const float* __restrict__ h,
                                                  const char* __restrict__ imgWout,
                                                  const float* __restrict__ bo,
                                                  float* __restrict__ out) {
    int bid = blockIdx.x;
    int rowblk = bid >> 3, nc = bid & 7;
    int tid = threadIdx.x, w = tid >> 6, lane = tid & 63;
    int l15 = lane & 15, kg = lane >> 4;
    int m0 = rowblk * 64 + w * 16;
    const float* hr = h + (size_t)(m0 + l15) * H;
    short8 a[4];
#pragma unroll
    for (int ks = 0; ks < 4; ks++) a[ks] = cvtfrag(hr + ks * 32 + kg * 8);
    f32x4 acc[8];
#pragma unroll
    for (int nt = 0; nt < 8; nt++) { f32x4 z = {0.f,0.f,0.f,0.f}; acc[nt] = z; }
#pragma unroll
    for (int ks = 0; ks < 4; ks++) {
        const char* bp = imgWout + (size_t)(nc * 128) * 256 + ks * 64 + kg * 16;
#pragma unroll
        for (int nt = 0; nt < 8; nt++) {
            short8 b = *(const short8*)(bp + (nt * 16 + l15) * 256);
            acc[nt] = __builtin_amdgcn_mfma_f32_16x16x32_bf16(a[ks], b, acc[nt], 0, 0, 0);
        }
    }
#pragma unroll
    for (int nt = 0; nt < 8; nt++) {
        int cc = nc * 128 + nt * 16 + l15;
        float bb = bo[cc];
#pragma unroll
        for (int r = 0; r < 4; r++)
            out[(size_t)(m0 + kg * 4 + r) * 1024 + cc] = acc[nt][r] + bb;
    }
}

extern "C" void kernel_launch(void* const* d_in, const int* in_sizes, int n_in,
                              void* d_out, int out_size, void* d_ws, size_t ws_size,
                              hipStream_t stream) {
    const float* y     = (const float*)d_in[0];
    const float* gc    = (const float*)d_in[1];
    const int*   ei    = (const int*)  d_in[2];
    const float* W_in  = (const float*)d_in[3];
    const float* b_in  = (const float*)d_in[4];
    const float* ln_g  = (const float*)d_in[5];
    const float* ln_b  = (const float*)d_in[6];
    const float* eW1   = (const float*)d_in[7];
    const float* eb1   = (const float*)d_in[8];
    const float* eW2   = (const float*)d_in[9];
    const float* eb2   = (const float*)d_in[10];
    const float* nW1   = (const float*)d_in[11];
    const float* nb1   = (const float*)d_in[12];
    const float* nW2   = (const float*)d_in[13];
    const float* nb2   = (const float*)d_in[14];
    const float* W_out = (const float*)d_in[15];
    const float* b_out = (const float*)d_in[16];

    int E = in_sizes[2] / 2;
    const int* rows = ei;
    const int* cols = ei + E;

    char* wsb = (char*)d_ws;
    float* h      = (float*)(wsb + OFF_H);
    float* hn     = (float*)(wsb + OFF_HN);
    float* P      = (float*)(wsb + OFF_PBUF);
    char*  aggb   = wsb + OFF_AGGB;
    float* deginv = (float*)(wsb + OFF_DEGI);
    int*   rowptr = (int*)(wsb + OFF_RPTR);
    float* dist   = (float*)(wsb + OFF_DIST);
    unsigned short* m1 = (unsigned short*)(wsb + OFF_M1);

    // pick chunk count so m1 chunk fits in ws (chunks = whole samples, Ec = E/nc exact)
    int nc = 16;
    for (int c = 1; c <= 16; c <<= 1) {
        if ((size_t)OFF_M1 + ((size_t)(E / c) + 32) * 256 <= ws_size) { nc = c; break; }
    }
    int Ec = E / nc;
    int Nc = NN / nc;

    k_prep<<<655360 / 256, 256, 0, stream>>>(W_in, W_out, eW1, nW1, nW2, eW2, wsb);
    k_rowptr<<<(NN + 1 + 255) / 256, 256, 0, stream>>>(rows, E, rowptr, deginv);
    k_dist<<<(E + 255) / 256, 256, 0, stream>>>(rows, cols, gc, E, dist);
    k_in_mfma<<<NN / 64, 256, 0, stream>>>(y, wsb + OFF_WIN, b_in, h);
    for (int l = 0; l < 4; ++l) {
        k_ln<<<NN / 4, 256, 0, stream>>>(h, ln_g + l * H, ln_b + l * H, hn);
        k_P_mfma<<<NN / 64 * 2, 256, 0, stream>>>(hn, wsb + OFF_P + (size_t)l * 65536,
                                                  eb1 + l * H, P);
        const float* w256f = eW1 + (size_t)l * 257 * H + 256 * H;
        for (int c = 0; c < nc; ++c) {
            k_m1<<<(Ec * 32 + 255) / 256, 256, 0, stream>>>(P, dist, rows, cols, w256f,
                                                            m1, Ec, c * Ec);
            k_edge2<<<Nc / 4, 256, 0, stream>>>(m1, rowptr, deginv,
                                                wsb + OFF_W2 + (size_t)l * 32768,
                                                eb2 + l * H, aggb, c * Nc, c * Ec);
        }
        k_node_mfma<<<NN / 64, 256, 0, stream>>>(hn, aggb,
                                                 wsb + OFF_N1 + (size_t)l * 65536, nb1 + l * H,
                                                 wsb + OFF_N2 + (size_t)l * 32768, nb2 + l * H, h);
    }
    k_out_mfma<<<NN / 64 * 8, 256, 0, stream>>>(h, wsb + OFF_WOUT, b_out, (float*)d_out);
}